// Round 1
// baseline (720.572 us; speedup 1.0000x reference)
//
#include <hip/hip_runtime.h>
#include <math.h>

#define NN 50000
#define NE 800000
#define SLOPE 0.2f

__device__ __forceinline__ float wave_sum(float v){
#pragma unroll
  for (int off = 32; off > 0; off >>= 1) v += __shfl_xor(v, off, 64);
  return v;
}
__device__ __forceinline__ float wave_max(float v){
#pragma unroll
  for (int off = 32; off > 0; off >>= 1) v = fmaxf(v, __shfl_xor(v, off, 64));
  return v;
}

// ---------------- CSR build (by dst) ----------------
__global__ void k_hist(const int* __restrict__ ei, int* __restrict__ counts){
  int e = blockIdx.x * 256 + threadIdx.x;
  if (e < NE) atomicAdd(&counts[ei[NE + e]], 1);
}

__global__ void k_scan1(const int* __restrict__ counts, int* __restrict__ row_ptr,
                        int* __restrict__ bsum){
  __shared__ int s[256];
  int t = threadIdx.x; int i = blockIdx.x * 256 + t;
  int v = (i < NN) ? counts[i] : 0;
  s[t] = v; __syncthreads();
  for (int off = 1; off < 256; off <<= 1){
    int add = (t >= off) ? s[t - off] : 0;
    __syncthreads();
    s[t] += add;
    __syncthreads();
  }
  int incl = s[t];
  if (i < NN) row_ptr[i + 1] = incl;
  if (t == 255) bsum[blockIdx.x] = incl;
}

__global__ void k_scan2(const int* __restrict__ bsum, int* __restrict__ boff, int nb){
  __shared__ int s[256];
  int t = threadIdx.x;
  int v = (t < nb) ? bsum[t] : 0;
  s[t] = v; __syncthreads();
  for (int off = 1; off < 256; off <<= 1){
    int add = (t >= off) ? s[t - off] : 0;
    __syncthreads();
    s[t] += add;
    __syncthreads();
  }
  if (t < nb) boff[t] = s[t] - v;   // exclusive block offset
}

__global__ void k_scan3(int* __restrict__ row_ptr, const int* __restrict__ boff,
                        const int* __restrict__ counts, int* __restrict__ cursor){
  int t = threadIdx.x; int i = blockIdx.x * 256 + t;
  if (i < NN){
    int v = row_ptr[i + 1] + boff[blockIdx.x];
    row_ptr[i + 1] = v;
    cursor[i] = v - counts[i];      // = exclusive start = row_ptr[i]
    if (i == 0) row_ptr[0] = 0;
  }
}

__global__ void k_scatter(const int* __restrict__ ei, int* __restrict__ cursor,
                          int* __restrict__ csr_src){
  int e = blockIdx.x * 256 + threadIdx.x;
  if (e < NE){
    int s = ei[e], d = ei[NE + e];
    int pos = atomicAdd(&cursor[d], 1);
    csr_src[pos] = s;
  }
}

// ---------------- Dual GEMM: Yl = X@Wl + bl, Yr = X@Wr + br ----------------
// Block: 256 threads, tile 32 rows x DO cols. X tile staged in LDS once,
// shared between both output matrices. W reads broadcast-cached in L1/L2.
template<int DI, int DO, int DO_PAD>
__global__ __launch_bounds__(256) void gemm_dual(
    const float* __restrict__ X,
    const float* __restrict__ Wl, const float* __restrict__ bl,
    const float* __restrict__ Wr, const float* __restrict__ br,
    float* __restrict__ Yl, float* __restrict__ Yr)
{
  constexpr int GROUPS = 256 / DO_PAD;
  constexpr int ROWS = 32;
  constexpr int RPT = ROWS / GROUPS;
  __shared__ float Xs[ROWS][DI];
  int tid = threadIdx.x;
  int row0 = blockIdx.x * ROWS;

  // stage X tile (float4, zero-fill OOB rows)
  constexpr int T4 = ROWS * DI / 4;
  for (int t4 = tid; t4 < T4; t4 += 256){
    int r = t4 / (DI / 4);
    int kk = t4 % (DI / 4);
    int row = row0 + r;
    float4 v = make_float4(0.f, 0.f, 0.f, 0.f);
    if (row < NN) v = reinterpret_cast<const float4*>(X + row * DI)[kk];
    reinterpret_cast<float4*>(&Xs[0][0])[t4] = v;
  }
  __syncthreads();

  int col = tid % DO_PAD;
  int g   = tid / DO_PAD;
  bool colok = (col < DO);
  float accl[RPT], accr[RPT];
#pragma unroll
  for (int i = 0; i < RPT; i++){ accl[i] = 0.f; accr[i] = 0.f; }

  for (int k = 0; k < DI; k++){
    float wl = colok ? Wl[k * DO + col] : 0.f;
    float wr = colok ? Wr[k * DO + col] : 0.f;
#pragma unroll
    for (int i = 0; i < RPT; i++){
      float x = Xs[g * RPT + i][k];   // wave-uniform address -> LDS broadcast
      accl[i] = fmaf(x, wl, accl[i]);
      accr[i] = fmaf(x, wr, accr[i]);
    }
  }
  if (colok){
    float vbl = bl[col], vbr = br[col];
#pragma unroll
    for (int i = 0; i < RPT; i++){
      int row = row0 + g * RPT + i;
      if (row < NN){
        Yl[row * DO + col] = accl[i] + vbl;
        Yr[row * DO + col] = accr[i] + vbr;
      }
    }
  }
}

// ---------------- Fused GATv2 aggregate: one wave per dst node ----------------
// Online softmax over incoming edges (self-loop handled implicitly as edge 0).
// ACT=0: relu epilogue. ACT=1: bias + log_softmax epilogue (DO=40, writes d_out).
template<int DO, int CPL, int ACT>
__global__ __launch_bounds__(256) void gat_agg(
    const float* __restrict__ xl, const float* __restrict__ xr,
    const int* __restrict__ csr_src, const int* __restrict__ row_ptr,
    const float* __restrict__ att, const float* __restrict__ bias,
    float* __restrict__ out)
{
  int wid = (blockIdx.x * 256 + threadIdx.x) >> 6;   // node
  int lane = threadIdx.x & 63;
  if (wid >= NN) return;
  int cbase = lane * CPL;

  float attv[CPL], xrv[CPL], xlv[CPL], acc[CPL];
#pragma unroll
  for (int j = 0; j < CPL; j++){
    int c = cbase + j;
    bool ok = (c < DO);
    attv[j] = ok ? att[c] : 0.f;
    xrv[j]  = ok ? xr[wid * DO + c] : 0.f;
    xlv[j]  = ok ? xl[wid * DO + c] : 0.f;
  }

  // self loop as first edge: src == dst
  float part = 0.f;
#pragma unroll
  for (int j = 0; j < CPL; j++){
    float t = xlv[j] + xrv[j];
    t = (t > 0.f) ? t : SLOPE * t;
    part = fmaf(t, attv[j], part);
  }
  float m = wave_sum(part);   // logit of self loop
  float den = 1.0f;
#pragma unroll
  for (int j = 0; j < CPL; j++) acc[j] = xlv[j];

  int e0 = row_ptr[wid], e1 = row_ptr[wid + 1];
  for (int e = e0; e < e1; e++){
    int src = csr_src[e];
    float xls[CPL];
#pragma unroll
    for (int j = 0; j < CPL; j++){
      int c = cbase + j;
      xls[j] = (c < DO) ? xl[src * DO + c] : 0.f;
    }
    float p2 = 0.f;
#pragma unroll
    for (int j = 0; j < CPL; j++){
      float t = xls[j] + xrv[j];
      t = (t > 0.f) ? t : SLOPE * t;
      p2 = fmaf(t, attv[j], p2);
    }
    float lg = wave_sum(p2);
    float mn = fmaxf(m, lg);
    float sc = __expf(m - mn);
    float p  = __expf(lg - mn);
    den = den * sc + p;
#pragma unroll
    for (int j = 0; j < CPL; j++) acc[j] = acc[j] * sc + p * xls[j];
    m = mn;
  }

  float inv = 1.0f / den;
  if (ACT == 0){
#pragma unroll
    for (int j = 0; j < CPL; j++){
      int c = cbase + j;
      if (c < DO){
        float v = acc[j] * inv + bias[c];
        out[wid * DO + c] = fmaxf(v, 0.f);
      }
    }
  } else {
    // DO=40, CPL=1: fused bias + log_softmax across the wave
    bool ok = (cbase < DO);
    float v = ok ? (acc[0] * inv + bias[cbase]) : -INFINITY;
    float mx = wave_max(v);
    float ex = ok ? __expf(v - mx) : 0.f;
    float s  = wave_sum(ex);
    if (ok) out[wid * DO + cbase] = v - mx - __logf(s);
  }
}

extern "C" void kernel_launch(void* const* d_in, const int* in_sizes, int n_in,
                              void* d_out, int out_size, void* d_ws, size_t ws_size,
                              hipStream_t stream) {
  const float* x   = (const float*)d_in[0];
  const int*   ei  = (const int*)d_in[1];
  const float* W1l = (const float*)d_in[2];  const float* W1r = (const float*)d_in[3];
  const float* b1l = (const float*)d_in[4];  const float* b1r = (const float*)d_in[5];
  const float* a1  = (const float*)d_in[6];  const float* c1  = (const float*)d_in[7];
  const float* W2l = (const float*)d_in[8];  const float* W2r = (const float*)d_in[9];
  const float* b2l = (const float*)d_in[10]; const float* b2r = (const float*)d_in[11];
  const float* a2  = (const float*)d_in[12]; const float* c2  = (const float*)d_in[13];
  const float* W3l = (const float*)d_in[14]; const float* W3r = (const float*)d_in[15];
  const float* b3l = (const float*)d_in[16]; const float* b3r = (const float*)d_in[17];
  const float* a3  = (const float*)d_in[18]; const float* c3  = (const float*)d_in[19];
  float* outp = (float*)d_out;

  // workspace layout
  float* xl = (float*)d_ws;          // 50000*128
  float* xr = xl + 6400000;          // 50000*128
  float* h1 = xr + 6400000;          // 50000*128
  float* h2 = h1 + 6400000;          // 50000*64
  int* counts  = (int*)(h2 + 3200000);   // 50000
  int* row_ptr = counts + 50000;         // 50001
  int* bsum    = row_ptr + 50001;        // 256
  int* boff    = bsum + 256;             // 256
  int* cursor  = boff + 256;             // 50000
  int* csr_src = cursor + 50000;         // 800000

  const int NB = (NN + 255) / 256;       // 196
  const int EB = (NE + 255) / 256;       // 3125
  const int GB = (NN + 31) / 32;         // 1563
  const int AB = (NN * 64 + 255) / 256;  // 12500

  // CSR build (per call; d_ws is re-poisoned before every launch)
  hipMemsetAsync(counts, 0, NN * sizeof(int), stream);
  k_hist<<<EB, 256, 0, stream>>>(ei, counts);
  k_scan1<<<NB, 256, 0, stream>>>(counts, row_ptr, bsum);
  k_scan2<<<1, 256, 0, stream>>>(bsum, boff, NB);
  k_scan3<<<NB, 256, 0, stream>>>(row_ptr, boff, counts, cursor);
  k_scatter<<<EB, 256, 0, stream>>>(ei, cursor, csr_src);

  // layer 1: 256 -> 128, relu
  gemm_dual<256,128,128><<<GB, 256, 0, stream>>>(x, W1l, b1l, W1r, b1r, xl, xr);
  gat_agg<128,2,0><<<AB, 256, 0, stream>>>(xl, xr, csr_src, row_ptr, a1, c1, h1);

  // layer 2: 128 -> 64, relu
  gemm_dual<128,64,64><<<GB, 256, 0, stream>>>(h1, W2l, b2l, W2r, b2r, xl, xr);
  gat_agg<64,1,0><<<AB, 256, 0, stream>>>(xl, xr, csr_src, row_ptr, a2, c2, h2);

  // layer 3: 64 -> 40, bias + log_softmax fused
  gemm_dual<64,40,64><<<GB, 256, 0, stream>>>(h2, W3l, b3l, W3r, b3r, xl, xr);
  gat_agg<40,1,1><<<AB, 256, 0, stream>>>(xl, xr, csr_src, row_ptr, a3, c3, outp);
}

// Round 2
// 632.283 us; speedup vs baseline: 1.1396x; 1.1396x over previous
//
#include <hip/hip_runtime.h>
#include <math.h>

#define NN 50000
#define NE 800000
#define SLOPE 0.2f

typedef short v8s __attribute__((ext_vector_type(8)));
typedef float v4f __attribute__((ext_vector_type(4)));

__device__ __forceinline__ float wave_sum(float v){
#pragma unroll
  for (int off = 32; off > 0; off >>= 1) v += __shfl_xor(v, off, 64);
  return v;
}
__device__ __forceinline__ float wave_max(float v){
#pragma unroll
  for (int off = 32; off > 0; off >>= 1) v = fmaxf(v, __shfl_xor(v, off, 64));
  return v;
}
__device__ __forceinline__ unsigned short f2bf(float f){
  unsigned int u = __float_as_uint(f);
  u = u + 0x7FFFu + ((u >> 16) & 1u);   // RNE
  return (unsigned short)(u >> 16);
}

// ---------------- CSR build (by dst) ----------------
__global__ void k_hist(const int* __restrict__ ei, int* __restrict__ counts){
  int e = blockIdx.x * 256 + threadIdx.x;
  if (e < NE) atomicAdd(&counts[ei[NE + e]], 1);
}

__global__ void k_scan1(const int* __restrict__ counts, int* __restrict__ row_ptr,
                        int* __restrict__ bsum){
  __shared__ int s[256];
  int t = threadIdx.x; int i = blockIdx.x * 256 + t;
  int v = (i < NN) ? counts[i] : 0;
  s[t] = v; __syncthreads();
  for (int off = 1; off < 256; off <<= 1){
    int add = (t >= off) ? s[t - off] : 0;
    __syncthreads();
    s[t] += add;
    __syncthreads();
  }
  int incl = s[t];
  if (i < NN) row_ptr[i + 1] = incl;
  if (t == 255) bsum[blockIdx.x] = incl;
}

__global__ void k_scan2(const int* __restrict__ bsum, int* __restrict__ boff, int nb){
  __shared__ int s[256];
  int t = threadIdx.x;
  int v = (t < nb) ? bsum[t] : 0;
  s[t] = v; __syncthreads();
  for (int off = 1; off < 256; off <<= 1){
    int add = (t >= off) ? s[t - off] : 0;
    __syncthreads();
    s[t] += add;
    __syncthreads();
  }
  if (t < nb) boff[t] = s[t] - v;   // exclusive block offset
}

__global__ void k_scan3(int* __restrict__ row_ptr, const int* __restrict__ boff,
                        const int* __restrict__ counts, int* __restrict__ cursor){
  int t = threadIdx.x; int i = blockIdx.x * 256 + t;
  if (i < NN){
    int v = row_ptr[i + 1] + boff[blockIdx.x];
    row_ptr[i + 1] = v;
    cursor[i] = v - counts[i];      // exclusive start = row_ptr[i]
    if (i == 0) row_ptr[0] = 0;
  }
}

__global__ void k_scatter(const int* __restrict__ ei, int* __restrict__ cursor,
                          int* __restrict__ csr_src){
  int e = blockIdx.x * 256 + threadIdx.x;
  if (e < NE){
    int s = ei[e], d = ei[NE + e];
    int pos = atomicAdd(&cursor[d], 1);
    csr_src[pos] = s;
  }
}

// ---------------- W pack: fp32 [K][DO] -> bf16 B-fragment order ----------------
// Fragment layout for mfma_f32_16x16x32_bf16 B operand:
//   lane holds B[k = c*32 + (lane>>4)*8 + j][col = nt*16 + (lane&15)], j=0..7
// Packed flat: Wp[((nt*KC + c)*64 + lane)*8 + j]  (16 B contiguous per lane)
__global__ void k_packW(const float* __restrict__ W, unsigned short* __restrict__ Wp,
                        int DO, int K, int NT){
  int t = blockIdx.x * 256 + threadIdx.x;
  int KC = K >> 5;
  int total = NT * KC * 64;
  if (t >= total) return;
  int lane = t & 63;
  int rest = t >> 6;
  int c  = rest % KC;
  int nt = rest / KC;
  int col = nt * 16 + (lane & 15);
  int k0  = c * 32 + ((lane >> 4) << 3);
  unsigned short o[8];
#pragma unroll
  for (int j = 0; j < 8; j++){
    float v = (col < DO) ? W[(k0 + j) * DO + col] : 0.f;
    o[j] = f2bf(v);
  }
  ulonglong2* dst = (ulonglong2*)(Wp + (size_t)t * 8);
  *dst = *(ulonglong2*)o;
}

// ---------------- MFMA dual GEMM: Yl = X@Wl + bl, Yr = X@Wr + br ----------------
// Block: 128 threads (2 waves). Block tile: 64 rows x full N. Wave: 32 rows.
// X staged in LDS as bf16 (padded rows), W read pre-packed from global (L2).
template<int K, int DO>
__global__ __launch_bounds__(128) void gemm_mfma(
    const float* __restrict__ X,
    const unsigned short* __restrict__ Wpl, const float* __restrict__ bl,
    const unsigned short* __restrict__ Wpr, const float* __restrict__ br,
    float* __restrict__ Yl, float* __restrict__ Yr)
{
  constexpr int KC = K / 32;
  constexpr int NT = (DO + 15) / 16;
  constexpr int LK = K + 8;              // padded row stride (ushorts)
  __shared__ unsigned short As[64 * LK];

  int tid = threadIdx.x;
  int wave = tid >> 6, lane = tid & 63;
  int row0 = blockIdx.x * 64;

  // stage X tile -> bf16 LDS
  constexpr int T4 = 64 * K / 4;
  for (int i = tid; i < T4; i += 128){
    int r  = i / (K / 4);
    int c4 = i % (K / 4);
    float4 v = make_float4(0.f, 0.f, 0.f, 0.f);
    if (row0 + r < NN) v = reinterpret_cast<const float4*>(X + (size_t)(row0 + r) * K)[c4];
    ushort4 o;
    o.x = f2bf(v.x); o.y = f2bf(v.y); o.z = f2bf(v.z); o.w = f2bf(v.w);
    *reinterpret_cast<ushort4*>(&As[r * LK + c4 * 4]) = o;
  }
  __syncthreads();

  // A fragments: wave covers rows [wave*32, wave*32+32) = two 16-row m-tiles
  int mrow = wave * 32;
  int arow = lane & 15;
  int aoff = (lane >> 4) << 3;
  v8s afrag[2][KC];
#pragma unroll
  for (int m = 0; m < 2; m++)
#pragma unroll
    for (int c = 0; c < KC; c++)
      afrag[m][c] = *reinterpret_cast<const v8s*>(&As[(mrow + m * 16 + arow) * LK + c * 32 + aoff]);

#pragma unroll
  for (int side = 0; side < 2; side++){
    const unsigned short* Wp = side ? Wpr : Wpl;
    const float* bias = side ? br : bl;
    float* Y = side ? Yr : Yl;
    for (int nt = 0; nt < NT; nt++){
      v8s bfrag[KC];
#pragma unroll
      for (int c = 0; c < KC; c++)
        bfrag[c] = *reinterpret_cast<const v8s*>(Wp + (size_t)((nt * KC + c) * 64 + lane) * 8);
      v4f acc0 = {0.f, 0.f, 0.f, 0.f}, acc1 = {0.f, 0.f, 0.f, 0.f};
#pragma unroll
      for (int c = 0; c < KC; c++){
        acc0 = __builtin_amdgcn_mfma_f32_16x16x32_bf16(afrag[0][c], bfrag[c], acc0, 0, 0, 0);
        acc1 = __builtin_amdgcn_mfma_f32_16x16x32_bf16(afrag[1][c], bfrag[c], acc1, 0, 0, 0);
      }
      // epilogue: C/D layout col = lane&15, row = (lane>>4)*4 + reg
      int col = nt * 16 + (lane & 15);
      if (col < DO){
        float bv = bias[col];
        int rbase = row0 + mrow + ((lane >> 4) << 2);
#pragma unroll
        for (int r = 0; r < 4; r++){
          int row = rbase + r;
          if (row < NN) Y[(size_t)row * DO + col] = acc0[r] + bv;
          int row1 = rbase + 16 + r;
          if (row1 < NN) Y[(size_t)row1 * DO + col] = acc1[r] + bv;
        }
      }
    }
  }
}

// ---------------- Fused GATv2 aggregate: one wave per dst node ----------------
template<int DO, int CPL, int ACT>
__global__ __launch_bounds__(256) void gat_agg(
    const float* __restrict__ xl, const float* __restrict__ xr,
    const int* __restrict__ csr_src, const int* __restrict__ row_ptr,
    const float* __restrict__ att, const float* __restrict__ bias,
    float* __restrict__ out)
{
  int wid = (blockIdx.x * 256 + threadIdx.x) >> 6;   // node
  int lane = threadIdx.x & 63;
  if (wid >= NN) return;
  int cbase = lane * CPL;

  float attv[CPL], xrv[CPL], xlv[CPL], acc[CPL];
#pragma unroll
  for (int j = 0; j < CPL; j++){
    int c = cbase + j;
    bool ok = (c < DO);
    attv[j] = ok ? att[c] : 0.f;
    xrv[j]  = ok ? xr[(size_t)wid * DO + c] : 0.f;
    xlv[j]  = ok ? xl[(size_t)wid * DO + c] : 0.f;
  }

  // self loop as first edge: src == dst
  float part = 0.f;
#pragma unroll
  for (int j = 0; j < CPL; j++){
    float t = xlv[j] + xrv[j];
    t = (t > 0.f) ? t : SLOPE * t;
    part = fmaf(t, attv[j], part);
  }
  float m = wave_sum(part);   // logit of self loop
  float den = 1.0f;
#pragma unroll
  for (int j = 0; j < CPL; j++) acc[j] = xlv[j];

  int e0 = row_ptr[wid], e1 = row_ptr[wid + 1];
  for (int e = e0; e < e1; e++){
    int src = csr_src[e];
    float xls[CPL];
#pragma unroll
    for (int j = 0; j < CPL; j++){
      int c = cbase + j;
      xls[j] = (c < DO) ? xl[(size_t)src * DO + c] : 0.f;
    }
    float p2 = 0.f;
#pragma unroll
    for (int j = 0; j < CPL; j++){
      float t = xls[j] + xrv[j];
      t = (t > 0.f) ? t : SLOPE * t;
      p2 = fmaf(t, attv[j], p2);
    }
    float lg = wave_sum(p2);
    float mn = fmaxf(m, lg);
    float sc = __expf(m - mn);
    float p  = __expf(lg - mn);
    den = den * sc + p;
#pragma unroll
    for (int j = 0; j < CPL; j++) acc[j] = acc[j] * sc + p * xls[j];
    m = mn;
  }

  float inv = 1.0f / den;
  if (ACT == 0){
#pragma unroll
    for (int j = 0; j < CPL; j++){
      int c = cbase + j;
      if (c < DO){
        float v = acc[j] * inv + bias[c];
        out[(size_t)wid * DO + c] = fmaxf(v, 0.f);
      }
    }
  } else {
    // DO=40, CPL=1: fused bias + log_softmax across the wave
    bool ok = (cbase < DO);
    float v = ok ? (acc[0] * inv + bias[cbase]) : -INFINITY;
    float mx = wave_max(v);
    float ex = ok ? __expf(v - mx) : 0.f;
    float s  = wave_sum(ex);
    if (ok) out[(size_t)wid * DO + cbase] = v - mx - __logf(s);
  }
}

extern "C" void kernel_launch(void* const* d_in, const int* in_sizes, int n_in,
                              void* d_out, int out_size, void* d_ws, size_t ws_size,
                              hipStream_t stream) {
  const float* x   = (const float*)d_in[0];
  const int*   ei  = (const int*)d_in[1];
  const float* W1l = (const float*)d_in[2];  const float* W1r = (const float*)d_in[3];
  const float* b1l = (const float*)d_in[4];  const float* b1r = (const float*)d_in[5];
  const float* a1  = (const float*)d_in[6];  const float* c1  = (const float*)d_in[7];
  const float* W2l = (const float*)d_in[8];  const float* W2r = (const float*)d_in[9];
  const float* b2l = (const float*)d_in[10]; const float* b2r = (const float*)d_in[11];
  const float* a2  = (const float*)d_in[12]; const float* c2  = (const float*)d_in[13];
  const float* W3l = (const float*)d_in[14]; const float* W3r = (const float*)d_in[15];
  const float* b3l = (const float*)d_in[16]; const float* b3r = (const float*)d_in[17];
  const float* a3  = (const float*)d_in[18]; const float* c3  = (const float*)d_in[19];
  float* outp = (float*)d_out;

  // workspace layout (floats/ints)
  float* xl = (float*)d_ws;          // 50000*128
  float* xr = xl + 6400000;          // 50000*128
  float* h1 = xr + 6400000;          // 50000*128
  float* h2 = h1 + 6400000;          // 50000*64
  int* counts  = (int*)(h2 + 3200000);   // 50000
  int* row_ptr = counts + 50000;         // 50001
  int* bsum    = row_ptr + 50001;        // 256
  int* boff    = bsum + 256;             // 256
  int* cursor  = boff + 256;             // 50000 ints (dead after k_scatter)
  int* csr_src = cursor + 50000;         // 800000

  // packed bf16 weights reuse cursor's 200 KB after k_scatter (needs 176,128 B)
  unsigned short* wp1l = (unsigned short*)cursor;   // 8*8*64*8 = 32768
  unsigned short* wp1r = wp1l + 32768;
  unsigned short* wp2l = wp1r + 32768;              // 4*4*64*8 = 8192
  unsigned short* wp2r = wp2l + 8192;
  unsigned short* wp3l = wp2r + 8192;               // 3*2*64*8 = 3072
  unsigned short* wp3r = wp3l + 3072;

  const int NB = (NN + 255) / 256;       // 196
  const int EB = (NE + 255) / 256;       // 3125
  const int GB = (NN + 63) / 64;         // 782
  const int AB = (NN * 64 + 255) / 256;  // 12500

  // CSR build
  hipMemsetAsync(counts, 0, NN * sizeof(int), stream);
  k_hist<<<EB, 256, 0, stream>>>(ei, counts);
  k_scan1<<<NB, 256, 0, stream>>>(counts, row_ptr, bsum);
  k_scan2<<<1, 256, 0, stream>>>(bsum, boff, NB);
  k_scan3<<<NB, 256, 0, stream>>>(row_ptr, boff, counts, cursor);
  k_scatter<<<EB, 256, 0, stream>>>(ei, cursor, csr_src);

  // pack weights to bf16 fragment order (cursor region is dead now)
  k_packW<<<16, 256, 0, stream>>>(W1l, wp1l, 128, 256, 8);
  k_packW<<<16, 256, 0, stream>>>(W1r, wp1r, 128, 256, 8);
  k_packW<<<4, 256, 0, stream>>>(W2l, wp2l, 64, 128, 4);
  k_packW<<<4, 256, 0, stream>>>(W2r, wp2r, 64, 128, 4);
  k_packW<<<2, 256, 0, stream>>>(W3l, wp3l, 40, 64, 3);
  k_packW<<<2, 256, 0, stream>>>(W3r, wp3r, 40, 64, 3);

  // layer 1: 256 -> 128, relu
  gemm_mfma<256,128><<<GB, 128, 0, stream>>>(x, wp1l, b1l, wp1r, b1r, xl, xr);
  gat_agg<128,2,0><<<AB, 256, 0, stream>>>(xl, xr, csr_src, row_ptr, a1, c1, h1);

  // layer 2: 128 -> 64, relu
  gemm_mfma<128,64><<<GB, 128, 0, stream>>>(h1, wp2l, b2l, wp2r, b2r, xl, xr);
  gat_agg<64,1,0><<<AB, 256, 0, stream>>>(xl, xr, csr_src, row_ptr, a2, c2, h2);

  // layer 3: 64 -> 40, bias + log_softmax fused
  gemm_mfma<64,40><<<GB, 128, 0, stream>>>(h2, wp3l, b3l, wp3r, b3r, xl, xr);
  gat_agg<40,1,1><<<AB, 256, 0, stream>>>(xl, xr, csr_src, row_ptr, a3, c3, outp);
}

// Round 3
// 442.127 us; speedup vs baseline: 1.6298x; 1.4301x over previous
//
#include <hip/hip_runtime.h>
#include <math.h>

#define NN 50000
#define NE 800000
#define SLOPE 0.2f
#define NEGX (-1e30f)

typedef short v8s __attribute__((ext_vector_type(8)));
typedef float v4f __attribute__((ext_vector_type(4)));

__device__ __forceinline__ unsigned short f2bf(float f){
  unsigned int u = __float_as_uint(f);
  u = u + 0x7FFFu + ((u >> 16) & 1u);   // RNE
  return (unsigned short)(u >> 16);
}

// ---------------- CSR build (by dst) ----------------
__global__ void k_hist(const int* __restrict__ ei, int* __restrict__ counts){
  int e = blockIdx.x * 256 + threadIdx.x;
  if (e < NE) atomicAdd(&counts[ei[NE + e]], 1);
}

__global__ void k_scan1(const int* __restrict__ counts, int* __restrict__ row_ptr,
                        int* __restrict__ bsum){
  __shared__ int s[256];
  int t = threadIdx.x; int i = blockIdx.x * 256 + t;
  int v = (i < NN) ? counts[i] : 0;
  s[t] = v; __syncthreads();
  for (int off = 1; off < 256; off <<= 1){
    int add = (t >= off) ? s[t - off] : 0;
    __syncthreads();
    s[t] += add;
    __syncthreads();
  }
  int incl = s[t];
  if (i < NN) row_ptr[i + 1] = incl;
  if (t == 255) bsum[blockIdx.x] = incl;
}

__global__ void k_scan2(const int* __restrict__ bsum, int* __restrict__ boff, int nb){
  __shared__ int s[256];
  int t = threadIdx.x;
  int v = (t < nb) ? bsum[t] : 0;
  s[t] = v; __syncthreads();
  for (int off = 1; off < 256; off <<= 1){
    int add = (t >= off) ? s[t - off] : 0;
    __syncthreads();
    s[t] += add;
    __syncthreads();
  }
  if (t < nb) boff[t] = s[t] - v;   // exclusive block offset
}

__global__ void k_scan3(int* __restrict__ row_ptr, const int* __restrict__ boff,
                        const int* __restrict__ counts, int* __restrict__ cursor){
  int t = threadIdx.x; int i = blockIdx.x * 256 + t;
  if (i < NN){
    int v = row_ptr[i + 1] + boff[blockIdx.x];
    row_ptr[i + 1] = v;
    cursor[i] = v - counts[i];      // exclusive start = row_ptr[i]
    if (i == 0) row_ptr[0] = 0;
  }
}

__global__ void k_scatter(const int* __restrict__ ei, int* __restrict__ cursor,
                          int* __restrict__ csr_src){
  int e = blockIdx.x * 256 + threadIdx.x;
  if (e < NE){
    int s = ei[e], d = ei[NE + e];
    int pos = atomicAdd(&cursor[d], 1);
    csr_src[pos] = s;
  }
}

// ---------------- W pack: fp32 [K][DO] -> bf16 B-fragment order ----------------
__global__ void k_packW(const float* __restrict__ W, unsigned short* __restrict__ Wp,
                        int DO, int K, int NT){
  int t = blockIdx.x * 256 + threadIdx.x;
  int KC = K >> 5;
  int total = NT * KC * 64;
  if (t >= total) return;
  int lane = t & 63;
  int rest = t >> 6;
  int c  = rest % KC;
  int nt = rest / KC;
  int col = nt * 16 + (lane & 15);
  int k0  = c * 32 + ((lane >> 4) << 3);
  unsigned short o[8];
#pragma unroll
  for (int j = 0; j < 8; j++){
    float v = (col < DO) ? W[(k0 + j) * DO + col] : 0.f;
    o[j] = f2bf(v);
  }
  ulonglong2* dst = (ulonglong2*)(Wp + (size_t)t * 8);
  *dst = *(ulonglong2*)o;
}

// ---------------- MFMA dual GEMM: Yl = bf16(X@Wl + bl), Yr = bf16(X@Wr + br) ----
template<int K, int DO>
__global__ __launch_bounds__(128) void gemm_mfma(
    const float* __restrict__ X,
    const unsigned short* __restrict__ Wpl, const float* __restrict__ bl,
    const unsigned short* __restrict__ Wpr, const float* __restrict__ br,
    unsigned short* __restrict__ Yl, unsigned short* __restrict__ Yr)
{
  constexpr int KC = K / 32;
  constexpr int NT = (DO + 15) / 16;
  constexpr int LK = K + 8;              // padded row stride (ushorts)
  __shared__ unsigned short As[64 * LK];

  int tid = threadIdx.x;
  int wave = tid >> 6, lane = tid & 63;
  int row0 = blockIdx.x * 64;

  constexpr int T4 = 64 * K / 4;
  for (int i = tid; i < T4; i += 128){
    int r  = i / (K / 4);
    int c4 = i % (K / 4);
    float4 v = make_float4(0.f, 0.f, 0.f, 0.f);
    if (row0 + r < NN) v = reinterpret_cast<const float4*>(X + (size_t)(row0 + r) * K)[c4];
    ushort4 o;
    o.x = f2bf(v.x); o.y = f2bf(v.y); o.z = f2bf(v.z); o.w = f2bf(v.w);
    *reinterpret_cast<ushort4*>(&As[r * LK + c4 * 4]) = o;
  }
  __syncthreads();

  int mrow = wave * 32;
  int arow = lane & 15;
  int aoff = (lane >> 4) << 3;
  v8s afrag[2][KC];
#pragma unroll
  for (int m = 0; m < 2; m++)
#pragma unroll
    for (int c = 0; c < KC; c++)
      afrag[m][c] = *reinterpret_cast<const v8s*>(&As[(mrow + m * 16 + arow) * LK + c * 32 + aoff]);

#pragma unroll
  for (int side = 0; side < 2; side++){
    const unsigned short* Wp = side ? Wpr : Wpl;
    const float* bias = side ? br : bl;
    unsigned short* Y = side ? Yr : Yl;
    for (int nt = 0; nt < NT; nt++){
      v8s bfrag[KC];
#pragma unroll
      for (int c = 0; c < KC; c++)
        bfrag[c] = *reinterpret_cast<const v8s*>(Wp + (size_t)((nt * KC + c) * 64 + lane) * 8);
      v4f acc0 = {0.f, 0.f, 0.f, 0.f}, acc1 = {0.f, 0.f, 0.f, 0.f};
#pragma unroll
      for (int c = 0; c < KC; c++){
        acc0 = __builtin_amdgcn_mfma_f32_16x16x32_bf16(afrag[0][c], bfrag[c], acc0, 0, 0, 0);
        acc1 = __builtin_amdgcn_mfma_f32_16x16x32_bf16(afrag[1][c], bfrag[c], acc1, 0, 0, 0);
      }
      int col = nt * 16 + (lane & 15);
      if (col < DO){
        float bv = bias[col];
        int rbase = row0 + mrow + ((lane >> 4) << 2);
#pragma unroll
        for (int r = 0; r < 4; r++){
          int row = rbase + r;
          if (row < NN) Y[(size_t)row * DO + col] = f2bf(acc0[r] + bv);
          int row1 = rbase + 16 + r;
          if (row1 < NN) Y[(size_t)row1 * DO + col] = f2bf(acc1[r] + bv);
        }
      }
    }
  }
}

// ---------------- Fused GATv2 aggregate ----------------
// One wave per dst node. Wave split into G = 64/LPG groups; each group keeps
// TWO independent online-softmax states (pair-unrolled edge loop) -> up to
// 2G edges in flight. States merged lane-locally, then across groups by shfl.
template<int DO>
__device__ __forceinline__ void load4(const unsigned short* __restrict__ base,
                                      int row, int cbase, bool ok, float* o){
  if (ok){
    ushort4 u = *reinterpret_cast<const ushort4*>(base + (size_t)row * DO + cbase);
    o[0] = __uint_as_float((unsigned)u.x << 16);
    o[1] = __uint_as_float((unsigned)u.y << 16);
    o[2] = __uint_as_float((unsigned)u.z << 16);
    o[3] = __uint_as_float((unsigned)u.w << 16);
  } else { o[0] = o[1] = o[2] = o[3] = 0.f; }
}

template<int LPG>
__device__ __forceinline__ float gsum(float v){
#pragma unroll
  for (int off = 1; off < LPG; off <<= 1) v += __shfl_xor(v, off, 64);
  return v;
}
template<int LPG>
__device__ __forceinline__ float gmax(float v){
#pragma unroll
  for (int off = 1; off < LPG; off <<= 1) v = fmaxf(v, __shfl_xor(v, off, 64));
  return v;
}

__device__ __forceinline__ void os_update(float& m, float& den, float* acc,
                                          float lg, const float* x){
  float mn = fmaxf(m, lg);
  float sc = __expf(m - mn);
  float p  = __expf(lg - mn);
  den = den * sc + p;
#pragma unroll
  for (int j = 0; j < 4; j++) acc[j] = fmaf(p, x[j], acc[j] * sc);
  m = mn;
}

template<int DO, int LPG, int ACT>
__global__ __launch_bounds__(256) void gat_agg(
    const unsigned short* __restrict__ xl, const unsigned short* __restrict__ xr,
    const int* __restrict__ csr_src, const int* __restrict__ row_ptr,
    const float* __restrict__ att, const float* __restrict__ bias,
    float* __restrict__ out)
{
  constexpr int G = 64 / LPG;
  int wid = (blockIdx.x * 256 + threadIdx.x) >> 6;   // node
  int lane = threadIdx.x & 63;
  if (wid >= NN) return;
  int g = lane / LPG;
  int p = lane % LPG;
  int cbase = p * 4;
  bool ok = (cbase < DO);

  float attv[4], xrv[4];
#pragma unroll
  for (int j = 0; j < 4; j++) attv[j] = (ok) ? att[cbase + j] : 0.f;
  load4<DO>(xr, wid, cbase, ok, xrv);

  float mA = NEGX, dA = 0.f, aA[4] = {0.f, 0.f, 0.f, 0.f};
  float mB = NEGX, dB = 0.f, aB[4] = {0.f, 0.f, 0.f, 0.f};

  // self loop -> group 0 state A
  if (g == 0){
    float xlv[4];
    load4<DO>(xl, wid, cbase, ok, xlv);
    float part = 0.f;
#pragma unroll
    for (int j = 0; j < 4; j++){
      float t = xlv[j] + xrv[j];
      t = (t > 0.f) ? t : SLOPE * t;
      part = fmaf(t, attv[j], part);
    }
    part = gsum<LPG>(part);
    mA = part; dA = 1.f;
#pragma unroll
    for (int j = 0; j < 4; j++) aA[j] = xlv[j];
  }

  int e0 = row_ptr[wid], e1 = row_ptr[wid + 1];
  int e = e0 + g;
  while (e + G < e1){
    int sA = csr_src[e];
    int sB = csr_src[e + G];
    float xA[4], xB[4];
    load4<DO>(xl, sA, cbase, ok, xA);
    load4<DO>(xl, sB, cbase, ok, xB);
    float pA = 0.f, pB = 0.f;
#pragma unroll
    for (int j = 0; j < 4; j++){
      float tA = xA[j] + xrv[j];
      tA = (tA > 0.f) ? tA : SLOPE * tA;
      pA = fmaf(tA, attv[j], pA);
      float tB = xB[j] + xrv[j];
      tB = (tB > 0.f) ? tB : SLOPE * tB;
      pB = fmaf(tB, attv[j], pB);
    }
    pA = gsum<LPG>(pA);
    pB = gsum<LPG>(pB);
    os_update(mA, dA, aA, pA, xA);
    os_update(mB, dB, aB, pB, xB);
    e += 2 * G;
  }
  if (e < e1){
    int sA = csr_src[e];
    float xA[4];
    load4<DO>(xl, sA, cbase, ok, xA);
    float pA = 0.f;
#pragma unroll
    for (int j = 0; j < 4; j++){
      float t = xA[j] + xrv[j];
      t = (t > 0.f) ? t : SLOPE * t;
      pA = fmaf(t, attv[j], pA);
    }
    pA = gsum<LPG>(pA);
    os_update(mA, dA, aA, pA, xA);
  }

  // merge B into A (lane-local)
  float m, den, acc[4];
  {
    float mn = fmaxf(mA, mB);
    float sa = __expf(mA - mn), sb = __expf(mB - mn);
    den = dA * sa + dB * sb;
#pragma unroll
    for (int j = 0; j < 4; j++) acc[j] = aA[j] * sa + aB[j] * sb;
    m = mn;
  }
  // merge across groups (lanes with same p hold same features)
#pragma unroll
  for (int off = LPG; off <= 32; off <<= 1){
    float mo = __shfl_xor(m, off, 64);
    float dno = __shfl_xor(den, off, 64);
    float ao[4];
#pragma unroll
    for (int j = 0; j < 4; j++) ao[j] = __shfl_xor(acc[j], off, 64);
    float mn = fmaxf(m, mo);
    float s1 = __expf(m - mn), s2 = __expf(mo - mn);
    den = den * s1 + dno * s2;
#pragma unroll
    for (int j = 0; j < 4; j++) acc[j] = acc[j] * s1 + ao[j] * s2;
    m = mn;
  }

  float inv = 1.0f / den;
  if (ACT == 0){
    if (g == 0 && ok){
      float4 o;
      o.x = fmaxf(fmaf(acc[0], inv, bias[cbase + 0]), 0.f);
      o.y = fmaxf(fmaf(acc[1], inv, bias[cbase + 1]), 0.f);
      o.z = fmaxf(fmaf(acc[2], inv, bias[cbase + 2]), 0.f);
      o.w = fmaxf(fmaf(acc[3], inv, bias[cbase + 3]), 0.f);
      *reinterpret_cast<float4*>(out + (size_t)wid * DO + cbase) = o;
    }
  } else {
    // DO=40: fused bias + log_softmax
    float v[4]; float lmax = NEGX;
#pragma unroll
    for (int j = 0; j < 4; j++){
      v[j] = ok ? (fmaf(acc[j], inv, bias[cbase + j])) : NEGX;
      lmax = fmaxf(lmax, v[j]);
    }
    lmax = gmax<LPG>(lmax);
    float lsum = 0.f;
#pragma unroll
    for (int j = 0; j < 4; j++) lsum += ok ? __expf(v[j] - lmax) : 0.f;
    lsum = gsum<LPG>(lsum);
    if (g == 0 && ok){
      float lg = lmax + __logf(lsum);
      float4 o;
      o.x = v[0] - lg; o.y = v[1] - lg; o.z = v[2] - lg; o.w = v[3] - lg;
      *reinterpret_cast<float4*>(out + (size_t)wid * DO + cbase) = o;
    }
  }
}

extern "C" void kernel_launch(void* const* d_in, const int* in_sizes, int n_in,
                              void* d_out, int out_size, void* d_ws, size_t ws_size,
                              hipStream_t stream) {
  const float* x   = (const float*)d_in[0];
  const int*   ei  = (const int*)d_in[1];
  const float* W1l = (const float*)d_in[2];  const float* W1r = (const float*)d_in[3];
  const float* b1l = (const float*)d_in[4];  const float* b1r = (const float*)d_in[5];
  const float* a1  = (const float*)d_in[6];  const float* c1  = (const float*)d_in[7];
  const float* W2l = (const float*)d_in[8];  const float* W2r = (const float*)d_in[9];
  const float* b2l = (const float*)d_in[10]; const float* b2r = (const float*)d_in[11];
  const float* a2  = (const float*)d_in[12]; const float* c2  = (const float*)d_in[13];
  const float* W3l = (const float*)d_in[14]; const float* W3r = (const float*)d_in[15];
  const float* b3l = (const float*)d_in[16]; const float* b3r = (const float*)d_in[17];
  const float* a3  = (const float*)d_in[18]; const float* c3  = (const float*)d_in[19];
  float* outp = (float*)d_out;

  // workspace layout
  unsigned short* xl = (unsigned short*)d_ws;   // 50000*128 bf16
  unsigned short* xr = xl + 6400000;            // 50000*128 bf16
  float* h1 = (float*)(xr + 6400000);           // 50000*128 f32
  float* h2 = h1 + 6400000;                     // 50000*64  f32
  int* counts  = (int*)(h2 + 3200000);   // 50000
  int* row_ptr = counts + 50000;         // 50001
  int* bsum    = row_ptr + 50001;        // 256
  int* boff    = bsum + 256;             // 256
  int* cursor  = boff + 256;             // 50000 ints (dead after k_scatter)
  int* csr_src = cursor + 50000;         // 800000

  unsigned short* wp1l = (unsigned short*)cursor;   // packed weights reuse cursor
  unsigned short* wp1r = wp1l + 32768;
  unsigned short* wp2l = wp1r + 32768;
  unsigned short* wp2r = wp2l + 8192;
  unsigned short* wp3l = wp2r + 8192;
  unsigned short* wp3r = wp3l + 3072;

  const int NB = (NN + 255) / 256;       // 196
  const int EB = (NE + 255) / 256;       // 3125
  const int GB = (NN + 63) / 64;         // 782
  const int AB = (NN * 64 + 255) / 256;  // 12500

  // CSR build
  hipMemsetAsync(counts, 0, NN * sizeof(int), stream);
  k_hist<<<EB, 256, 0, stream>>>(ei, counts);
  k_scan1<<<NB, 256, 0, stream>>>(counts, row_ptr, bsum);
  k_scan2<<<1, 256, 0, stream>>>(bsum, boff, NB);
  k_scan3<<<NB, 256, 0, stream>>>(row_ptr, boff, counts, cursor);
  k_scatter<<<EB, 256, 0, stream>>>(ei, cursor, csr_src);

  // pack weights to bf16 fragment order (cursor region dead now)
  k_packW<<<16, 256, 0, stream>>>(W1l, wp1l, 128, 256, 8);
  k_packW<<<16, 256, 0, stream>>>(W1r, wp1r, 128, 256, 8);
  k_packW<<<4, 256, 0, stream>>>(W2l, wp2l, 64, 128, 4);
  k_packW<<<4, 256, 0, stream>>>(W2r, wp2r, 64, 128, 4);
  k_packW<<<2, 256, 0, stream>>>(W3l, wp3l, 40, 64, 3);
  k_packW<<<2, 256, 0, stream>>>(W3r, wp3r, 40, 64, 3);

  // layer 1: 256 -> 128, relu
  gemm_mfma<256,128><<<GB, 128, 0, stream>>>(x, wp1l, b1l, wp1r, b1r, xl, xr);
  gat_agg<128,32,0><<<AB, 256, 0, stream>>>(xl, xr, csr_src, row_ptr, a1, c1, h1);

  // layer 2: 128 -> 64, relu
  gemm_mfma<128,64><<<GB, 128, 0, stream>>>(h1, wp2l, b2l, wp2r, b2r, xl, xr);
  gat_agg<64,16,0><<<AB, 256, 0, stream>>>(xl, xr, csr_src, row_ptr, a2, c2, h2);

  // layer 3: 64 -> 40, bias + log_softmax fused
  gemm_mfma<64,40><<<GB, 128, 0, stream>>>(h2, wp3l, b3l, wp3r, b3r, xl, xr);
  gat_agg<40,16,1><<<AB, 256, 0, stream>>>(xl, xr, csr_src, row_ptr, a3, c3, outp);
}

// Round 4
// 439.125 us; speedup vs baseline: 1.6409x; 1.0068x over previous
//
#include <hip/hip_runtime.h>
#include <math.h>

#define NN 50000
#define NE 800000
#define SLOPE 0.2f
#define NEGX (-1e30f)

typedef short v8s __attribute__((ext_vector_type(8)));
typedef float v4f __attribute__((ext_vector_type(4)));

__device__ __forceinline__ unsigned short f2bf(float f){
  unsigned int u = __float_as_uint(f);
  u = u + 0x7FFFu + ((u >> 16) & 1u);   // RNE
  return (unsigned short)(u >> 16);
}

// ---------------- CSR build (by dst) ----------------
__global__ void k_hist(const int* __restrict__ ei, int* __restrict__ counts){
  int e = blockIdx.x * 256 + threadIdx.x;
  if (e < NE) atomicAdd(&counts[ei[NE + e]], 1);
}

__global__ void k_scan1(const int* __restrict__ counts, int* __restrict__ row_ptr,
                        int* __restrict__ bsum){
  __shared__ int s[256];
  int t = threadIdx.x; int i = blockIdx.x * 256 + t;
  int v = (i < NN) ? counts[i] : 0;
  s[t] = v; __syncthreads();
  for (int off = 1; off < 256; off <<= 1){
    int add = (t >= off) ? s[t - off] : 0;
    __syncthreads();
    s[t] += add;
    __syncthreads();
  }
  int incl = s[t];
  if (i < NN) row_ptr[i + 1] = incl;
  if (t == 255) bsum[blockIdx.x] = incl;
}

__global__ void k_scan2(const int* __restrict__ bsum, int* __restrict__ boff, int nb){
  __shared__ int s[256];
  int t = threadIdx.x;
  int v = (t < nb) ? bsum[t] : 0;
  s[t] = v; __syncthreads();
  for (int off = 1; off < 256; off <<= 1){
    int add = (t >= off) ? s[t - off] : 0;
    __syncthreads();
    s[t] += add;
    __syncthreads();
  }
  if (t < nb) boff[t] = s[t] - v;   // exclusive block offset
}

__global__ void k_scan3(int* __restrict__ row_ptr, const int* __restrict__ boff,
                        const int* __restrict__ counts, int* __restrict__ cursor){
  int t = threadIdx.x; int i = blockIdx.x * 256 + t;
  if (i < NN){
    int v = row_ptr[i + 1] + boff[blockIdx.x];
    row_ptr[i + 1] = v;
    cursor[i] = v - counts[i];      // exclusive start = row_ptr[i]
    if (i == 0) row_ptr[0] = 0;
  }
}

__global__ void k_scatter(const int* __restrict__ ei, int* __restrict__ cursor,
                          int* __restrict__ csr_src){
  int e = blockIdx.x * 256 + threadIdx.x;
  if (e < NE){
    int s = ei[e], d = ei[NE + e];
    int pos = atomicAdd(&cursor[d], 1);
    csr_src[pos] = s;
  }
}

// ---------------- W pack: fp32 [K][DO] -> bf16 B-fragment order ----------------
__global__ void k_packW(const float* __restrict__ W, unsigned short* __restrict__ Wp,
                        int DO, int K, int NT){
  int t = blockIdx.x * 256 + threadIdx.x;
  int KC = K >> 5;
  int total = NT * KC * 64;
  if (t >= total) return;
  int lane = t & 63;
  int rest = t >> 6;
  int c  = rest % KC;
  int nt = rest / KC;
  int col = nt * 16 + (lane & 15);
  int k0  = c * 32 + ((lane >> 4) << 3);
  unsigned short o[8];
#pragma unroll
  for (int j = 0; j < 8; j++){
    float v = (col < DO) ? W[(k0 + j) * DO + col] : 0.f;
    o[j] = f2bf(v);
  }
  ulonglong2* dst = (ulonglong2*)(Wp + (size_t)t * 8);
  *dst = *(ulonglong2*)o;
}

// ---------------- MFMA dual GEMM: Yl = bf16(X@Wl + bl), Yr = bf16(X@Wr + br) ----
// TI = float (fp32 input, converted) or unsigned short (bf16 input, copied).
template<typename TI, int K, int DO>
__global__ __launch_bounds__(128) void gemm_mfma(
    const TI* __restrict__ X,
    const unsigned short* __restrict__ Wpl, const float* __restrict__ bl,
    const unsigned short* __restrict__ Wpr, const float* __restrict__ br,
    unsigned short* __restrict__ Yl, unsigned short* __restrict__ Yr)
{
  constexpr int KC = K / 32;
  constexpr int NT = (DO + 15) / 16;
  constexpr int LK = K + 8;              // padded row stride (ushorts)
  __shared__ unsigned short As[64 * LK];

  int tid = threadIdx.x;
  int wave = tid >> 6, lane = tid & 63;
  int row0 = blockIdx.x * 64;

  if constexpr (sizeof(TI) == 4){
    constexpr int T4 = 64 * K / 4;
    for (int i = tid; i < T4; i += 128){
      int r  = i / (K / 4);
      int c4 = i % (K / 4);
      float4 v = make_float4(0.f, 0.f, 0.f, 0.f);
      if (row0 + r < NN) v = reinterpret_cast<const float4*>(X + (size_t)(row0 + r) * K)[c4];
      ushort4 o;
      o.x = f2bf(v.x); o.y = f2bf(v.y); o.z = f2bf(v.z); o.w = f2bf(v.w);
      *reinterpret_cast<ushort4*>(&As[r * LK + c4 * 4]) = o;
    }
  } else {
    constexpr int T8 = 64 * K / 8;
    for (int i = tid; i < T8; i += 128){
      int r  = i / (K / 8);
      int c8 = i % (K / 8);
      uint4 v = make_uint4(0u, 0u, 0u, 0u);
      if (row0 + r < NN)
        v = reinterpret_cast<const uint4*>(X + (size_t)(row0 + r) * K)[c8];
      *reinterpret_cast<uint4*>(&As[r * LK + c8 * 8]) = v;
    }
  }
  __syncthreads();

  int mrow = wave * 32;
  int arow = lane & 15;
  int aoff = (lane >> 4) << 3;
  v8s afrag[2][KC];
#pragma unroll
  for (int m = 0; m < 2; m++)
#pragma unroll
    for (int c = 0; c < KC; c++)
      afrag[m][c] = *reinterpret_cast<const v8s*>(&As[(mrow + m * 16 + arow) * LK + c * 32 + aoff]);

#pragma unroll
  for (int side = 0; side < 2; side++){
    const unsigned short* Wp = side ? Wpr : Wpl;
    const float* bias = side ? br : bl;
    unsigned short* Y = side ? Yr : Yl;
    for (int nt = 0; nt < NT; nt++){
      v8s bfrag[KC];
#pragma unroll
      for (int c = 0; c < KC; c++)
        bfrag[c] = *reinterpret_cast<const v8s*>(Wp + (size_t)((nt * KC + c) * 64 + lane) * 8);
      v4f acc0 = {0.f, 0.f, 0.f, 0.f}, acc1 = {0.f, 0.f, 0.f, 0.f};
#pragma unroll
      for (int c = 0; c < KC; c++){
        acc0 = __builtin_amdgcn_mfma_f32_16x16x32_bf16(afrag[0][c], bfrag[c], acc0, 0, 0, 0);
        acc1 = __builtin_amdgcn_mfma_f32_16x16x32_bf16(afrag[1][c], bfrag[c], acc1, 0, 0, 0);
      }
      int col = nt * 16 + (lane & 15);
      if (col < DO){
        float bv = bias[col];
        int rbase = row0 + mrow + ((lane >> 4) << 2);
#pragma unroll
        for (int r = 0; r < 4; r++){
          int row = rbase + r;
          if (row < NN) Y[(size_t)row * DO + col] = f2bf(acc0[r] + bv);
          int row1 = rbase + 16 + r;
          if (row1 < NN) Y[(size_t)row1 * DO + col] = f2bf(acc1[r] + bv);
        }
      }
    }
  }
}

// ---------------- Fused GATv2 aggregate ----------------
// One wave per dst node, G = 64/LPG groups of LPG lanes, 8 features/lane.
// NO max subtraction: logits are O(±8) (Glorot-scale), exp() is safe in fp32.
// So each group just accumulates den += exp(logit), acc += exp(logit)*x, and
// cross-group/state merges are plain adds.
__device__ __forceinline__ void unpack8(uint4 u, float* o){
  o[0] = __uint_as_float(u.x << 16); o[1] = __uint_as_float(u.x & 0xffff0000u);
  o[2] = __uint_as_float(u.y << 16); o[3] = __uint_as_float(u.y & 0xffff0000u);
  o[4] = __uint_as_float(u.z << 16); o[5] = __uint_as_float(u.z & 0xffff0000u);
  o[6] = __uint_as_float(u.w << 16); o[7] = __uint_as_float(u.w & 0xffff0000u);
}

template<int LPG>
__device__ __forceinline__ float gsum(float v){
#pragma unroll
  for (int off = 1; off < LPG; off <<= 1) v += __shfl_xor(v, off, 64);
  return v;
}
template<int LPG>
__device__ __forceinline__ void gsum2(float& a, float& b){
#pragma unroll
  for (int off = 1; off < LPG; off <<= 1){
    a += __shfl_xor(a, off, 64);
    b += __shfl_xor(b, off, 64);
  }
}
template<int LPG>
__device__ __forceinline__ float gmax(float v){
#pragma unroll
  for (int off = 1; off < LPG; off <<= 1) v = fmaxf(v, __shfl_xor(v, off, 64));
  return v;
}

template<int DO, int LPG, int ACT, typename OT>
__global__ __launch_bounds__(256) void gat_agg(
    const unsigned short* __restrict__ xl, const unsigned short* __restrict__ xr,
    const int* __restrict__ csr_src, const int* __restrict__ row_ptr,
    const float* __restrict__ att, const float* __restrict__ bias,
    OT* __restrict__ out)
{
  constexpr int G = 64 / LPG;
  int wid = (blockIdx.x * 256 + threadIdx.x) >> 6;   // node
  int lane = threadIdx.x & 63;
  if (wid >= NN) return;
  int g = lane / LPG;
  int p = lane % LPG;
  int cbase = p * 8;
  bool ok = (LPG * 8 <= DO) ? true : (cbase < DO);

  float attv[8], xrv[8];
#pragma unroll
  for (int j = 0; j < 8; j++) attv[j] = ok ? att[cbase + j] : 0.f;
  if (ok) unpack8(*reinterpret_cast<const uint4*>(xr + wid * DO + cbase), xrv);
  else { for (int j = 0; j < 8; j++) xrv[j] = 0.f; }

  float denA = 0.f, denB = 0.f;
  float accA[8], accB[8];
#pragma unroll
  for (int j = 0; j < 8; j++){ accA[j] = 0.f; accB[j] = 0.f; }

  // self loop (group 0 only)
  if (g == 0){
    float xlv[8];
    if (ok) unpack8(*reinterpret_cast<const uint4*>(xl + wid * DO + cbase), xlv);
    else { for (int j = 0; j < 8; j++) xlv[j] = 0.f; }
    float s = 0.f;
#pragma unroll
    for (int j = 0; j < 8; j++){
      float t = xlv[j] + xrv[j];
      t = fmaxf(t, SLOPE * t);
      s = fmaf(t, attv[j], s);
    }
    s = gsum<LPG>(s);
    float w = __expf(s);
    denA = w;
#pragma unroll
    for (int j = 0; j < 8; j++) accA[j] = w * xlv[j];
  }

  int e0 = row_ptr[wid], e1 = row_ptr[wid + 1];
  int e = e0 + g;
  while (e + G < e1){
    int sA = csr_src[e];
    int sB = csr_src[e + G];
    float xA[8], xB[8];
    if (ok){
      unpack8(*reinterpret_cast<const uint4*>(xl + sA * DO + cbase), xA);
      unpack8(*reinterpret_cast<const uint4*>(xl + sB * DO + cbase), xB);
    } else {
#pragma unroll
      for (int j = 0; j < 8; j++){ xA[j] = 0.f; xB[j] = 0.f; }
    }
    float pA = 0.f, pB = 0.f;
#pragma unroll
    for (int j = 0; j < 8; j++){
      float tA = xA[j] + xrv[j];
      tA = fmaxf(tA, SLOPE * tA);
      pA = fmaf(tA, attv[j], pA);
      float tB = xB[j] + xrv[j];
      tB = fmaxf(tB, SLOPE * tB);
      pB = fmaf(tB, attv[j], pB);
    }
    gsum2<LPG>(pA, pB);
    float wA = __expf(pA), wB = __expf(pB);
    denA += wA; denB += wB;
#pragma unroll
    for (int j = 0; j < 8; j++){
      accA[j] = fmaf(wA, xA[j], accA[j]);
      accB[j] = fmaf(wB, xB[j], accB[j]);
    }
    e += 2 * G;
  }
  if (e < e1){
    int sA = csr_src[e];
    float xA[8];
    if (ok) unpack8(*reinterpret_cast<const uint4*>(xl + sA * DO + cbase), xA);
    else { for (int j = 0; j < 8; j++) xA[j] = 0.f; }
    float pA = 0.f;
#pragma unroll
    for (int j = 0; j < 8; j++){
      float t = xA[j] + xrv[j];
      t = fmaxf(t, SLOPE * t);
      pA = fmaf(t, attv[j], pA);
    }
    pA = gsum<LPG>(pA);
    float w = __expf(pA);
    denA += w;
#pragma unroll
    for (int j = 0; j < 8; j++) accA[j] = fmaf(w, xA[j], accA[j]);
  }

  float den = denA + denB;
  float acc[8];
#pragma unroll
  for (int j = 0; j < 8; j++) acc[j] = accA[j] + accB[j];

  // cross-group merge: plain sums
#pragma unroll
  for (int off = LPG; off <= 32; off <<= 1){
    den += __shfl_xor(den, off, 64);
#pragma unroll
    for (int j = 0; j < 8; j++) acc[j] += __shfl_xor(acc[j], off, 64);
  }

  float inv = 1.0f / den;
  if (ACT == 0){
    if (g == 0 && ok){
      float v[8];
#pragma unroll
      for (int j = 0; j < 8; j++) v[j] = fmaxf(fmaf(acc[j], inv, bias[cbase + j]), 0.f);
      uint4 o;
      o.x = (unsigned)f2bf(v[0]) | ((unsigned)f2bf(v[1]) << 16);
      o.y = (unsigned)f2bf(v[2]) | ((unsigned)f2bf(v[3]) << 16);
      o.z = (unsigned)f2bf(v[4]) | ((unsigned)f2bf(v[5]) << 16);
      o.w = (unsigned)f2bf(v[6]) | ((unsigned)f2bf(v[7]) << 16);
      *reinterpret_cast<uint4*>((unsigned short*)out + wid * DO + cbase) = o;
    }
  } else {
    // DO=40: fused bias + log_softmax (5 of 8 lanes active)
    float v[8]; float lmax = NEGX;
#pragma unroll
    for (int j = 0; j < 8; j++){
      v[j] = ok ? fmaf(acc[j], inv, bias[cbase + j]) : NEGX;
      lmax = fmaxf(lmax, v[j]);
    }
    lmax = gmax<LPG>(lmax);
    float lsum = 0.f;
#pragma unroll
    for (int j = 0; j < 8; j++) lsum += __expf(v[j] - lmax);   // idle lanes add exp(-1e30)=0
    lsum = gsum<LPG>(lsum);
    if (g == 0 && ok){
      float lg = lmax + __logf(lsum);
      float* op = (float*)out + wid * DO + cbase;
      float4 o0, o1;
      o0.x = v[0] - lg; o0.y = v[1] - lg; o0.z = v[2] - lg; o0.w = v[3] - lg;
      o1.x = v[4] - lg; o1.y = v[5] - lg; o1.z = v[6] - lg; o1.w = v[7] - lg;
      *reinterpret_cast<float4*>(op) = o0;
      *reinterpret_cast<float4*>(op + 4) = o1;
    }
  }
}

extern "C" void kernel_launch(void* const* d_in, const int* in_sizes, int n_in,
                              void* d_out, int out_size, void* d_ws, size_t ws_size,
                              hipStream_t stream) {
  const float* x   = (const float*)d_in[0];
  const int*   ei  = (const int*)d_in[1];
  const float* W1l = (const float*)d_in[2];  const float* W1r = (const float*)d_in[3];
  const float* b1l = (const float*)d_in[4];  const float* b1r = (const float*)d_in[5];
  const float* a1  = (const float*)d_in[6];  const float* c1  = (const float*)d_in[7];
  const float* W2l = (const float*)d_in[8];  const float* W2r = (const float*)d_in[9];
  const float* b2l = (const float*)d_in[10]; const float* b2r = (const float*)d_in[11];
  const float* a2  = (const float*)d_in[12]; const float* c2  = (const float*)d_in[13];
  const float* W3l = (const float*)d_in[14]; const float* W3r = (const float*)d_in[15];
  const float* b3l = (const float*)d_in[16]; const float* b3r = (const float*)d_in[17];
  const float* a3  = (const float*)d_in[18]; const float* c3  = (const float*)d_in[19];
  float* outp = (float*)d_out;

  // workspace layout
  unsigned short* xl = (unsigned short*)d_ws;   // 50000*128 bf16
  unsigned short* xr = xl + 6400000;            // 50000*128 bf16
  unsigned short* h1 = xr + 6400000;            // 50000*128 bf16
  unsigned short* h2 = h1 + 6400000;            // 50000*64  bf16
  int* counts  = (int*)(h2 + 3200000);   // 50000
  int* row_ptr = counts + 50000;         // 50001
  int* bsum    = row_ptr + 50001;        // 256
  int* boff    = bsum + 256;             // 256
  int* cursor  = boff + 256;             // 50000 ints (dead after k_scatter)
  int* csr_src = cursor + 50000;         // 800000

  unsigned short* wp1l = (unsigned short*)cursor;   // packed weights reuse cursor
  unsigned short* wp1r = wp1l + 32768;
  unsigned short* wp2l = wp1r + 32768;
  unsigned short* wp2r = wp2l + 8192;
  unsigned short* wp3l = wp2r + 8192;
  unsigned short* wp3r = wp3l + 3072;

  const int NB = (NN + 255) / 256;       // 196
  const int EB = (NE + 255) / 256;       // 3125
  const int GB = (NN + 63) / 64;         // 782
  const int AB = (NN * 64 + 255) / 256;  // 12500

  // CSR build
  hipMemsetAsync(counts, 0, NN * sizeof(int), stream);
  k_hist<<<EB, 256, 0, stream>>>(ei, counts);
  k_scan1<<<NB, 256, 0, stream>>>(counts, row_ptr, bsum);
  k_scan2<<<1, 256, 0, stream>>>(bsum, boff, NB);
  k_scan3<<<NB, 256, 0, stream>>>(row_ptr, boff, counts, cursor);
  k_scatter<<<EB, 256, 0, stream>>>(ei, cursor, csr_src);

  // pack weights to bf16 fragment order (cursor region dead now)
  k_packW<<<16, 256, 0, stream>>>(W1l, wp1l, 128, 256, 8);
  k_packW<<<16, 256, 0, stream>>>(W1r, wp1r, 128, 256, 8);
  k_packW<<<4, 256, 0, stream>>>(W2l, wp2l, 64, 128, 4);
  k_packW<<<4, 256, 0, stream>>>(W2r, wp2r, 64, 128, 4);
  k_packW<<<2, 256, 0, stream>>>(W3l, wp3l, 40, 64, 3);
  k_packW<<<2, 256, 0, stream>>>(W3r, wp3r, 40, 64, 3);

  // layer 1: 256 -> 128, relu
  gemm_mfma<float,256,128><<<GB, 128, 0, stream>>>(x, wp1l, b1l, wp1r, b1r, xl, xr);
  gat_agg<128,16,0><<<AB, 256, 0, stream>>>(xl, xr, csr_src, row_ptr, a1, c1, h1);

  // layer 2: 128 -> 64, relu
  gemm_mfma<unsigned short,128,64><<<GB, 128, 0, stream>>>(h1, wp2l, b2l, wp2r, b2r, xl, xr);
  gat_agg<64,8,0><<<AB, 256, 0, stream>>>(xl, xr, csr_src, row_ptr, a2, c2, h2);

  // layer 3: 64 -> 40, bias + log_softmax fused
  gemm_mfma<unsigned short,64,40><<<GB, 128, 0, stream>>>(h2, wp3l, b3l, wp3r, b3r, xl, xr);
  gat_agg<40,8,1><<<AB, 256, 0, stream>>>(xl, xr, csr_src, row_ptr, a3, c3, outp);
}

// Round 5
// 365.685 us; speedup vs baseline: 1.9705x; 1.2008x over previous
//
#include <hip/hip_runtime.h>
#include <math.h>

#define NN 50000
#define NE 800000
#define SLOPE 0.2f
#define NEGX (-1e30f)
#define NBK 256      // coarse buckets = dst>>8 (196 used)
#define CH 8192      // edges per k_bscatter block

typedef short v8s __attribute__((ext_vector_type(8)));
typedef float v4f __attribute__((ext_vector_type(4)));

__device__ __forceinline__ unsigned short f2bf(float f){
  unsigned int u = __float_as_uint(f);
  u = u + 0x7FFFu + ((u >> 16) & 1u);   // RNE
  return (unsigned short)(u >> 16);
}

// ---------------- fused weight pack (+ bucket-counter zeroing) ----------------
// Fragment layout for mfma_f32_16x16x32_bf16 B operand:
//   lane holds B[k = c*32 + (lane>>4)*8 + j][col = nt*16 + (lane&15)], j=0..7
__device__ __forceinline__ void pack_one(const float* __restrict__ W,
                                         unsigned short* __restrict__ Wp,
                                         int DO, int K, int NT, int t){
  int KC = K >> 5;
  if (t >= NT * KC * 64) return;
  int lane = t & 63;
  int rest = t >> 6;
  int c  = rest % KC;
  int nt = rest / KC;
  int col = nt * 16 + (lane & 15);
  int k0  = c * 32 + ((lane >> 4) << 3);
  unsigned short o[8];
#pragma unroll
  for (int j = 0; j < 8; j++){
    float v = (col < DO) ? W[(k0 + j) * DO + col] : 0.f;
    o[j] = f2bf(v);
  }
  *(ulonglong2*)(Wp + (size_t)t * 8) = *(ulonglong2*)o;
}

__global__ __launch_bounds__(256) void k_packAll(
    const float* W1l, const float* W1r, const float* W2l,
    const float* W2r, const float* W3l, const float* W3r,
    unsigned short* p1l, unsigned short* p1r, unsigned short* p2l,
    unsigned short* p2r, unsigned short* p3l, unsigned short* p3r,
    int* gb){
  int b = blockIdx.x, t = threadIdx.x;
  if      (b < 16) pack_one(W1l, p1l, 128, 256, 8, (b      ) * 256 + t);
  else if (b < 32) pack_one(W1r, p1r, 128, 256, 8, (b - 16 ) * 256 + t);
  else if (b < 36) pack_one(W2l, p2l,  64, 128, 4, (b - 32 ) * 256 + t);
  else if (b < 40) pack_one(W2r, p2r,  64, 128, 4, (b - 36 ) * 256 + t);
  else if (b < 42) pack_one(W3l, p3l,  40,  64, 3, (b - 40 ) * 256 + t);
  else if (b < 44) pack_one(W3r, p3r,  40,  64, 3, (b - 42 ) * 256 + t);
  else gb[t] = 0;   // block 44: zero the bucket counters
}

// ---------------- CSR build: two-level bucket sort ----------------
__global__ __launch_bounds__(256) void k_bhist(const int* __restrict__ ei,
                                               int* __restrict__ gb){
  __shared__ int h[NBK];
  int t = threadIdx.x;
  h[t] = 0;
  __syncthreads();
  for (int e = blockIdx.x * 256 + t; e < NE; e += gridDim.x * 256)
    atomicAdd(&h[ei[NE + e] >> 8], 1);
  __syncthreads();
  if (h[t]) atomicAdd(&gb[t], h[t]);
}

__global__ __launch_bounds__(256) void k_bscan(const int* __restrict__ gb,
                                               int* __restrict__ base,
                                               int* __restrict__ bcur,
                                               int* __restrict__ row_ptr){
  __shared__ int s[256];
  int t = threadIdx.x;
  int v = gb[t];
  s[t] = v; __syncthreads();
  for (int off = 1; off < 256; off <<= 1){
    int a = (t >= off) ? s[t - off] : 0;
    __syncthreads(); s[t] += a; __syncthreads();
  }
  int ex = s[t] - v;
  base[t] = ex;
  bcur[t] = ex;
  if (t == 255){ base[256] = s[255]; row_ptr[NN] = s[255]; }   // = NE
}

// pack: src (16b) | dstLow (8b) << 16 | bucket (8b) << 24
__global__ __launch_bounds__(256) void k_bscatter(const int* __restrict__ ei,
                                                  int* __restrict__ bcur,
                                                  unsigned* __restrict__ pk_out){
  __shared__ unsigned pk[CH];
  __shared__ int h[NBK];
  int t = threadIdx.x;
  int e0 = blockIdx.x * CH;
  h[t] = 0;
  __syncthreads();
  int n = NE - e0; if (n > CH) n = CH;
  for (int i = t; i < n; i += 256){
    int e = e0 + i;
    int s = ei[e], d = ei[NE + e];
    pk[i] = (unsigned)s | ((unsigned)(d & 255) << 16) | ((unsigned)(d >> 8) << 24);
    atomicAdd(&h[d >> 8], 1);
  }
  __syncthreads();
  int c = h[t];
  if (c) h[t] = atomicAdd(&bcur[t], c);
  __syncthreads();
  for (int i = t; i < n; i += 256){
    unsigned u = pk[i];
    int pos = atomicAdd(&h[u >> 24], 1);
    pk_out[pos] = u;
  }
}

__global__ __launch_bounds__(256) void k_bcsr(const unsigned* __restrict__ pk,
                                              const int* __restrict__ base,
                                              int* __restrict__ row_ptr,
                                              int* __restrict__ csr_src){
  __shared__ int h[256], s[256];
  int t = threadIdx.x;
  int b = blockIdx.x;
  int lo = base[b], hi = base[b + 1];
  h[t] = 0;
  __syncthreads();
  for (int i = lo + t; i < hi; i += 256)
    atomicAdd(&h[(pk[i] >> 16) & 255], 1);
  __syncthreads();
  int v = h[t];
  s[t] = v; __syncthreads();
  for (int off = 1; off < 256; off <<= 1){
    int a = (t >= off) ? s[t - off] : 0;
    __syncthreads(); s[t] += a; __syncthreads();
  }
  int ex = lo + s[t] - v;       // absolute exclusive start for dst = b*256+t
  int node = b * 256 + t;
  if (node < NN) row_ptr[node] = ex;
  h[t] = ex;                    // reuse as cursor
  __syncthreads();
  for (int i = lo + t; i < hi; i += 256){
    unsigned u = pk[i];
    int pos = atomicAdd(&h[(u >> 16) & 255], 1);
    csr_src[pos] = (int)(u & 0xFFFFu);
  }
}

// ---------------- MFMA dual GEMM: Yl = bf16(X@Wl + bl), Yr = bf16(X@Wr + br) ----
template<typename TI, int K, int DO>
__global__ __launch_bounds__(128) void gemm_mfma(
    const TI* __restrict__ X,
    const unsigned short* __restrict__ Wpl, const float* __restrict__ bl,
    const unsigned short* __restrict__ Wpr, const float* __restrict__ br,
    unsigned short* __restrict__ Yl, unsigned short* __restrict__ Yr)
{
  constexpr int KC = K / 32;
  constexpr int NT = (DO + 15) / 16;
  constexpr int LK = K + 8;
  __shared__ unsigned short As[64 * LK];

  int tid = threadIdx.x;
  int wave = tid >> 6, lane = tid & 63;
  int row0 = blockIdx.x * 64;

  if constexpr (sizeof(TI) == 4){
    constexpr int T4 = 64 * K / 4;
    for (int i = tid; i < T4; i += 128){
      int r  = i / (K / 4);
      int c4 = i % (K / 4);
      float4 v = make_float4(0.f, 0.f, 0.f, 0.f);
      if (row0 + r < NN) v = reinterpret_cast<const float4*>(X + (size_t)(row0 + r) * K)[c4];
      ushort4 o;
      o.x = f2bf(v.x); o.y = f2bf(v.y); o.z = f2bf(v.z); o.w = f2bf(v.w);
      *reinterpret_cast<ushort4*>(&As[r * LK + c4 * 4]) = o;
    }
  } else {
    constexpr int T8 = 64 * K / 8;
    for (int i = tid; i < T8; i += 128){
      int r  = i / (K / 8);
      int c8 = i % (K / 8);
      uint4 v = make_uint4(0u, 0u, 0u, 0u);
      if (row0 + r < NN)
        v = reinterpret_cast<const uint4*>(X + (size_t)(row0 + r) * K)[c8];
      *reinterpret_cast<uint4*>(&As[r * LK + c8 * 8]) = v;
    }
  }
  __syncthreads();

  int mrow = wave * 32;
  int arow = lane & 15;
  int aoff = (lane >> 4) << 3;
  v8s afrag[2][KC];
#pragma unroll
  for (int m = 0; m < 2; m++)
#pragma unroll
    for (int c = 0; c < KC; c++)
      afrag[m][c] = *reinterpret_cast<const v8s*>(&As[(mrow + m * 16 + arow) * LK + c * 32 + aoff]);

#pragma unroll
  for (int side = 0; side < 2; side++){
    const unsigned short* Wp = side ? Wpr : Wpl;
    const float* bias = side ? br : bl;
    unsigned short* Y = side ? Yr : Yl;
    for (int nt = 0; nt < NT; nt++){
      v8s bfrag[KC];
#pragma unroll
      for (int c = 0; c < KC; c++)
        bfrag[c] = *reinterpret_cast<const v8s*>(Wp + (size_t)((nt * KC + c) * 64 + lane) * 8);
      v4f acc0 = {0.f, 0.f, 0.f, 0.f}, acc1 = {0.f, 0.f, 0.f, 0.f};
#pragma unroll
      for (int c = 0; c < KC; c++){
        acc0 = __builtin_amdgcn_mfma_f32_16x16x32_bf16(afrag[0][c], bfrag[c], acc0, 0, 0, 0);
        acc1 = __builtin_amdgcn_mfma_f32_16x16x32_bf16(afrag[1][c], bfrag[c], acc1, 0, 0, 0);
      }
      int col = nt * 16 + (lane & 15);
      if (col < DO){
        float bv = bias[col];
        int rbase = row0 + mrow + ((lane >> 4) << 2);
#pragma unroll
        for (int r = 0; r < 4; r++){
          int row = rbase + r;
          if (row < NN) Y[(size_t)row * DO + col] = f2bf(acc0[r] + bv);
          int row1 = rbase + 16 + r;
          if (row1 < NN) Y[(size_t)row1 * DO + col] = f2bf(acc1[r] + bv);
        }
      }
    }
  }
}

// ---------------- Fused GATv2 aggregate ----------------
// One wave per dst node, G = 64/LPG groups, 8 features/lane, no max-subtract
// (Glorot-scale logits are O(±8); fp32 exp overflows at 88).
__device__ __forceinline__ void unpack8(uint4 u, float* o){
  o[0] = __uint_as_float(u.x << 16); o[1] = __uint_as_float(u.x & 0xffff0000u);
  o[2] = __uint_as_float(u.y << 16); o[3] = __uint_as_float(u.y & 0xffff0000u);
  o[4] = __uint_as_float(u.z << 16); o[5] = __uint_as_float(u.z & 0xffff0000u);
  o[6] = __uint_as_float(u.w << 16); o[7] = __uint_as_float(u.w & 0xffff0000u);
}

template<int LPG>
__device__ __forceinline__ float gsum(float v){
#pragma unroll
  for (int off = 1; off < LPG; off <<= 1) v += __shfl_xor(v, off, 64);
  return v;
}
template<int LPG>
__device__ __forceinline__ void gsum2(float& a, float& b){
#pragma unroll
  for (int off = 1; off < LPG; off <<= 1){
    a += __shfl_xor(a, off, 64);
    b += __shfl_xor(b, off, 64);
  }
}
template<int LPG>
__device__ __forceinline__ float gmax(float v){
#pragma unroll
  for (int off = 1; off < LPG; off <<= 1) v = fmaxf(v, __shfl_xor(v, off, 64));
  return v;
}

template<int DO, int LPG, int ACT, typename OT>
__global__ __launch_bounds__(256) void gat_agg(
    const unsigned short* __restrict__ xl, const unsigned short* __restrict__ xr,
    const int* __restrict__ csr_src, const int* __restrict__ row_ptr,
    const float* __restrict__ att, const float* __restrict__ bias,
    OT* __restrict__ out)
{
  constexpr int G = 64 / LPG;
  int wid = (blockIdx.x * 256 + threadIdx.x) >> 6;   // node
  int lane = threadIdx.x & 63;
  if (wid >= NN) return;
  int g = lane / LPG;
  int p = lane % LPG;
  int cbase = p * 8;
  bool ok = (LPG * 8 <= DO) ? true : (cbase < DO);

  float attv[8], xrv[8];
#pragma unroll
  for (int j = 0; j < 8; j++) attv[j] = ok ? att[cbase + j] : 0.f;
  if (ok) unpack8(*reinterpret_cast<const uint4*>(xr + wid * DO + cbase), xrv);
  else { for (int j = 0; j < 8; j++) xrv[j] = 0.f; }

  float denA = 0.f, denB = 0.f;
  float accA[8], accB[8];
#pragma unroll
  for (int j = 0; j < 8; j++){ accA[j] = 0.f; accB[j] = 0.f; }

  if (g == 0){
    float xlv[8];
    if (ok) unpack8(*reinterpret_cast<const uint4*>(xl + wid * DO + cbase), xlv);
    else { for (int j = 0; j < 8; j++) xlv[j] = 0.f; }
    float s = 0.f;
#pragma unroll
    for (int j = 0; j < 8; j++){
      float t = xlv[j] + xrv[j];
      t = fmaxf(t, SLOPE * t);
      s = fmaf(t, attv[j], s);
    }
    s = gsum<LPG>(s);
    float w = __expf(s);
    denA = w;
#pragma unroll
    for (int j = 0; j < 8; j++) accA[j] = w * xlv[j];
  }

  int e0 = row_ptr[wid], e1 = row_ptr[wid + 1];
  int e = e0 + g;
  while (e + G < e1){
    int sA = csr_src[e];
    int sB = csr_src[e + G];
    float xA[8], xB[8];
    if (ok){
      unpack8(*reinterpret_cast<const uint4*>(xl + sA * DO + cbase), xA);
      unpack8(*reinterpret_cast<const uint4*>(xl + sB * DO + cbase), xB);
    } else {
#pragma unroll
      for (int j = 0; j < 8; j++){ xA[j] = 0.f; xB[j] = 0.f; }
    }
    float pA = 0.f, pB = 0.f;
#pragma unroll
    for (int j = 0; j < 8; j++){
      float tA = xA[j] + xrv[j];
      tA = fmaxf(tA, SLOPE * tA);
      pA = fmaf(tA, attv[j], pA);
      float tB = xB[j] + xrv[j];
      tB = fmaxf(tB, SLOPE * tB);
      pB = fmaf(tB, attv[j], pB);
    }
    gsum2<LPG>(pA, pB);
    float wA = __expf(pA), wB = __expf(pB);
    denA += wA; denB += wB;
#pragma unroll
    for (int j = 0; j < 8; j++){
      accA[j] = fmaf(wA, xA[j], accA[j]);
      accB[j] = fmaf(wB, xB[j], accB[j]);
    }
    e += 2 * G;
  }
  if (e < e1){
    int sA = csr_src[e];
    float xA[8];
    if (ok) unpack8(*reinterpret_cast<const uint4*>(xl + sA * DO + cbase), xA);
    else { for (int j = 0; j < 8; j++) xA[j] = 0.f; }
    float pA = 0.f;
#pragma unroll
    for (int j = 0; j < 8; j++){
      float t = xA[j] + xrv[j];
      t = fmaxf(t, SLOPE * t);
      pA = fmaf(t, attv[j], pA);
    }
    pA = gsum<LPG>(pA);
    float w = __expf(pA);
    denA += w;
#pragma unroll
    for (int j = 0; j < 8; j++) accA[j] = fmaf(w, xA[j], accA[j]);
  }

  float den = denA + denB;
  float acc[8];
#pragma unroll
  for (int j = 0; j < 8; j++) acc[j] = accA[j] + accB[j];

#pragma unroll
  for (int off = LPG; off <= 32; off <<= 1){
    den += __shfl_xor(den, off, 64);
#pragma unroll
    for (int j = 0; j < 8; j++) acc[j] += __shfl_xor(acc[j], off, 64);
  }

  float inv = 1.0f / den;
  if (ACT == 0){
    if (g == 0 && ok){
      float v[8];
#pragma unroll
      for (int j = 0; j < 8; j++) v[j] = fmaxf(fmaf(acc[j], inv, bias[cbase + j]), 0.f);
      uint4 o;
      o.x = (unsigned)f2bf(v[0]) | ((unsigned)f2bf(v[1]) << 16);
      o.y = (unsigned)f2bf(v[2]) | ((unsigned)f2bf(v[3]) << 16);
      o.z = (unsigned)f2bf(v[4]) | ((unsigned)f2bf(v[5]) << 16);
      o.w = (unsigned)f2bf(v[6]) | ((unsigned)f2bf(v[7]) << 16);
      *reinterpret_cast<uint4*>((unsigned short*)out + wid * DO + cbase) = o;
    }
  } else {
    float v[8]; float lmax = NEGX;
#pragma unroll
    for (int j = 0; j < 8; j++){
      v[j] = ok ? fmaf(acc[j], inv, bias[cbase + j]) : NEGX;
      lmax = fmaxf(lmax, v[j]);
    }
    lmax = gmax<LPG>(lmax);
    float lsum = 0.f;
#pragma unroll
    for (int j = 0; j < 8; j++) lsum += __expf(v[j] - lmax);
    lsum = gsum<LPG>(lsum);
    if (g == 0 && ok){
      float lg = lmax + __logf(lsum);
      float* op = (float*)out + wid * DO + cbase;
      float4 o0, o1;
      o0.x = v[0] - lg; o0.y = v[1] - lg; o0.z = v[2] - lg; o0.w = v[3] - lg;
      o1.x = v[4] - lg; o1.y = v[5] - lg; o1.z = v[6] - lg; o1.w = v[7] - lg;
      *reinterpret_cast<float4*>(op) = o0;
      *reinterpret_cast<float4*>(op + 4) = o1;
    }
  }
}

extern "C" void kernel_launch(void* const* d_in, const int* in_sizes, int n_in,
                              void* d_out, int out_size, void* d_ws, size_t ws_size,
                              hipStream_t stream) {
  const float* x   = (const float*)d_in[0];
  const int*   ei  = (const int*)d_in[1];
  const float* W1l = (const float*)d_in[2];  const float* W1r = (const float*)d_in[3];
  const float* b1l = (const float*)d_in[4];  const float* b1r = (const float*)d_in[5];
  const float* a1  = (const float*)d_in[6];  const float* c1  = (const float*)d_in[7];
  const float* W2l = (const float*)d_in[8];  const float* W2r = (const float*)d_in[9];
  const float* b2l = (const float*)d_in[10]; const float* b2r = (const float*)d_in[11];
  const float* a2  = (const float*)d_in[12]; const float* c2  = (const float*)d_in[13];
  const float* W3l = (const float*)d_in[14]; const float* W3r = (const float*)d_in[15];
  const float* b3l = (const float*)d_in[16]; const float* b3r = (const float*)d_in[17];
  const float* a3  = (const float*)d_in[18]; const float* c3  = (const float*)d_in[19];
  float* outp = (float*)d_out;

  // workspace layout
  unsigned short* xl = (unsigned short*)d_ws;   // 50000*128 bf16
  unsigned short* xr = xl + 6400000;
  unsigned short* h1 = xr + 6400000;
  unsigned short* h2 = h1 + 6400000;            // 50000*64 bf16
  unsigned* pk    = (unsigned*)(h2 + 3200000);  // 800000 packed edges
  int* csr_src    = (int*)(pk + NE);            // 800000
  int* row_ptr    = csr_src + NE;               // 50001
  int* gb         = row_ptr + 50001;            // 256
  int* base       = gb + 256;                   // 257
  int* bcur       = base + 257;                 // 256
  unsigned short* wp1l = (unsigned short*)(bcur + 256);
  unsigned short* wp1r = wp1l + 32768;
  unsigned short* wp2l = wp1r + 32768;
  unsigned short* wp2r = wp2l + 8192;
  unsigned short* wp3l = wp2r + 8192;
  unsigned short* wp3r = wp3l + 3072;

  const int GB = (NN + 63) / 64;         // 782 gemm blocks
  const int AB = (NN * 64 + 255) / 256;  // 12500 agg blocks
  const int SB = (NE + CH - 1) / CH;     // 98 scatter blocks

  // weight pack + bucket-counter zero (one launch)
  k_packAll<<<45, 256, 0, stream>>>(W1l, W1r, W2l, W2r, W3l, W3r,
                                    wp1l, wp1r, wp2l, wp2r, wp3l, wp3r, gb);
  // CSR build: bucket hist -> scan -> bucket scatter -> per-bucket CSR
  k_bhist<<<256, 256, 0, stream>>>(ei, gb);
  k_bscan<<<1, 256, 0, stream>>>(gb, base, bcur, row_ptr);
  k_bscatter<<<SB, 256, 0, stream>>>(ei, bcur, pk);
  k_bcsr<<<196, 256, 0, stream>>>(pk, base, row_ptr, csr_src);

  // layer 1: 256 -> 128, relu
  gemm_mfma<float,256,128><<<GB, 128, 0, stream>>>(x, wp1l, b1l, wp1r, b1r, xl, xr);
  gat_agg<128,16,0><<<AB, 256, 0, stream>>>(xl, xr, csr_src, row_ptr, a1, c1, h1);

  // layer 2: 128 -> 64, relu
  gemm_mfma<unsigned short,128,64><<<GB, 128, 0, stream>>>(h1, wp2l, b2l, wp2r, b2r, xl, xr);
  gat_agg<64,8,0><<<AB, 256, 0, stream>>>(xl, xr, csr_src, row_ptr, a2, c2, h2);

  // layer 3: 64 -> 40, bias + log_softmax fused
  gemm_mfma<unsigned short,64,40><<<GB, 128, 0, stream>>>(h2, wp3l, b3l, wp3r, b3r, xl, xr);
  gat_agg<40,8,1><<<AB, 256, 0, stream>>>(xl, xr, csr_src, row_ptr, a3, c3, outp);
}

// Round 6
// 348.029 us; speedup vs baseline: 2.0704x; 1.0507x over previous
//
#include <hip/hip_runtime.h>
#include <math.h>

#define NN 50000
#define NE 800000
#define SLOPE 0.2f
#define NEGX (-1e30f)
#define CH 8192

typedef _Float16 h8 __attribute__((ext_vector_type(8)));
typedef _Float16 h4 __attribute__((ext_vector_type(4)));
typedef _Float16 h2 __attribute__((ext_vector_type(2)));
typedef float f8 __attribute__((ext_vector_type(8)));
typedef float v4f __attribute__((ext_vector_type(4)));

__device__ __forceinline__ h8 hzero(){ h8 z = {0,0,0,0,0,0,0,0}; return z; }

// ---------------- fused weight pack (fp16 fragment order) + edge histogram ----
// B-fragment layout for mfma_f32_16x16x32_f16:
//   lane holds B[k = c*32 + (lane>>4)*8 + j][col = nt*16 + (lane&15)], j=0..7
__device__ __forceinline__ void pack_one(const float* __restrict__ W,
                                         _Float16* __restrict__ Wp,
                                         int DO, int K, int NT, int t){
  int KC = K >> 5;
  if (t >= NT * KC * 64) return;
  int lane = t & 63;
  int rest = t >> 6;
  int c  = rest % KC;
  int nt = rest / KC;
  int col = nt * 16 + (lane & 15);
  int k0  = c * 32 + ((lane >> 4) << 3);
  _Float16 o[8];
#pragma unroll
  for (int j = 0; j < 8; j++){
    float v = (col < DO) ? W[(k0 + j) * DO + col] : 0.f;
    o[j] = (_Float16)v;
  }
  *(ulonglong2*)(Wp + (size_t)t * 8) = *(ulonglong2*)o;
}

__global__ __launch_bounds__(256) void k_pack_hist(
    const float* W1l, const float* W1r, const float* W2l,
    const float* W2r, const float* W3l, const float* W3r,
    _Float16* p1l, _Float16* p1r, _Float16* p2l,
    _Float16* p2r, _Float16* p3l, _Float16* p3r,
    const int* __restrict__ ei, int* __restrict__ gbp){
  __shared__ int h[256];
  int b = blockIdx.x, t = threadIdx.x;
  if (b < 44){
    if      (b < 16) pack_one(W1l, p1l, 128, 256, 8, (b     ) * 256 + t);
    else if (b < 32) pack_one(W1r, p1r, 128, 256, 8, (b - 16) * 256 + t);
    else if (b < 36) pack_one(W2l, p2l,  64, 128, 4, (b - 32) * 256 + t);
    else if (b < 40) pack_one(W2r, p2r,  64, 128, 4, (b - 36) * 256 + t);
    else if (b < 42) pack_one(W3l, p3l,  40,  64, 3, (b - 40) * 256 + t);
    else             pack_one(W3r, p3r,  40,  64, 3, (b - 42) * 256 + t);
  } else {
    int hb = b - 44;                 // 0..255, each owns 3125 edges
    h[t] = 0;
    __syncthreads();
    int e0 = hb * 3125;
    for (int i = t; i < 3125; i += 256)
      atomicAdd(&h[ei[NE + e0 + i] >> 8], 1);
    __syncthreads();
    gbp[hb * 256 + t] = h[t];        // non-atomic partial; all slots written
  }
}

// ---------------- scan: reduce partials, exclusive scan over 256 buckets ------
__global__ __launch_bounds__(256) void k_scan(const int* __restrict__ gbp,
                                              int* __restrict__ base,
                                              int* __restrict__ bcur,
                                              int* __restrict__ row_ptr){
  __shared__ int s[256];
  int t = threadIdx.x;
  int v = 0;
  for (int i = 0; i < 256; i++) v += gbp[i * 256 + t];
  s[t] = v; __syncthreads();
  for (int off = 1; off < 256; off <<= 1){
    int a = (t >= off) ? s[t - off] : 0;
    __syncthreads(); s[t] += a; __syncthreads();
  }
  int ex = s[t] - v;
  base[t] = ex;
  bcur[t] = ex;
  if (t == 255){ base[256] = s[255]; row_ptr[NN] = s[255]; }
}

// pack: src (16b) | dstLow (8b) << 16 | bucket (8b) << 24
__global__ __launch_bounds__(256) void k_bscatter(const int* __restrict__ ei,
                                                  int* __restrict__ bcur,
                                                  unsigned* __restrict__ pk_out){
  __shared__ unsigned pk[CH];
  __shared__ int h[256];
  int t = threadIdx.x;
  int e0 = blockIdx.x * CH;
  h[t] = 0;
  __syncthreads();
  int n = NE - e0; if (n > CH) n = CH;
  for (int i = t; i < n; i += 256){
    int e = e0 + i;
    int s = ei[e], d = ei[NE + e];
    pk[i] = (unsigned)s | ((unsigned)(d & 255) << 16) | ((unsigned)(d >> 8) << 24);
    atomicAdd(&h[d >> 8], 1);
  }
  __syncthreads();
  int c = h[t];
  if (c) h[t] = atomicAdd(&bcur[t], c);
  __syncthreads();
  for (int i = t; i < n; i += 256){
    unsigned u = pk[i];
    int pos = atomicAdd(&h[u >> 24], 1);
    pk_out[pos] = u;
  }
}

__global__ __launch_bounds__(256) void k_bcsr(const unsigned* __restrict__ pk,
                                              const int* __restrict__ base,
                                              int* __restrict__ row_ptr,
                                              int* __restrict__ csr_src){
  __shared__ int h[256], s[256];
  int t = threadIdx.x;
  int b = blockIdx.x;
  int lo = base[b], hi = base[b + 1];
  h[t] = 0;
  __syncthreads();
  for (int i = lo + t; i < hi; i += 256)
    atomicAdd(&h[(pk[i] >> 16) & 255], 1);
  __syncthreads();
  int v = h[t];
  s[t] = v; __syncthreads();
  for (int off = 1; off < 256; off <<= 1){
    int a = (t >= off) ? s[t - off] : 0;
    __syncthreads(); s[t] += a; __syncthreads();
  }
  int ex = lo + s[t] - v;
  int node = b * 256 + t;
  if (node < NN) row_ptr[node] = ex;
  h[t] = ex;
  __syncthreads();
  for (int i = lo + t; i < hi; i += 256){
    unsigned u = pk[i];
    int pos = atomicAdd(&h[(u >> 16) & 255], 1);
    csr_src[pos] = (int)(u & 0xFFFFu);
  }
}

// ---------------- MFMA dual GEMM (f16): Yl = f16(X@Wl+bl), Yr = f16(X@Wr+br) ---
template<typename TI, int K, int DO>
__global__ __launch_bounds__(128) void gemm_mfma(
    const TI* __restrict__ X,
    const _Float16* __restrict__ Wpl, const float* __restrict__ bl,
    const _Float16* __restrict__ Wpr, const float* __restrict__ br,
    _Float16* __restrict__ Yl, _Float16* __restrict__ Yr)
{
  constexpr int KC = K / 32;
  constexpr int NT = (DO + 15) / 16;
  constexpr int LK = K + 8;               // padded row stride (halves)
  __shared__ _Float16 As[64 * LK];

  int tid = threadIdx.x;
  int wave = tid >> 6, lane = tid & 63;
  int row0 = blockIdx.x * 64;

  if constexpr (sizeof(TI) == 4){
    constexpr int T4 = 64 * K / 4;
    for (int i = tid; i < T4; i += 128){
      int r  = i / (K / 4);
      int c4 = i % (K / 4);
      float4 v = make_float4(0.f, 0.f, 0.f, 0.f);
      if (row0 + r < NN) v = reinterpret_cast<const float4*>(X + (size_t)(row0 + r) * K)[c4];
      h4 o; o[0]=(_Float16)v.x; o[1]=(_Float16)v.y; o[2]=(_Float16)v.z; o[3]=(_Float16)v.w;
      *reinterpret_cast<h4*>(&As[r * LK + c4 * 4]) = o;
    }
  } else {
    constexpr int T8 = 64 * K / 8;
    for (int i = tid; i < T8; i += 128){
      int r  = i / (K / 8);
      int c8 = i % (K / 8);
      uint4 v = make_uint4(0u, 0u, 0u, 0u);
      if (row0 + r < NN)
        v = reinterpret_cast<const uint4*>(X + (size_t)(row0 + r) * K)[c8];
      *reinterpret_cast<uint4*>(&As[r * LK + c8 * 8]) = v;
    }
  }
  __syncthreads();

  int mrow = wave * 32;
  int arow = lane & 15;
  int aoff = (lane >> 4) << 3;
  h8 afrag[2][KC];
#pragma unroll
  for (int m = 0; m < 2; m++)
#pragma unroll
    for (int c = 0; c < KC; c++)
      afrag[m][c] = *reinterpret_cast<const h8*>(&As[(mrow + m * 16 + arow) * LK + c * 32 + aoff]);

#pragma unroll
  for (int side = 0; side < 2; side++){
    const _Float16* Wp = side ? Wpr : Wpl;
    const float* bias = side ? br : bl;
    _Float16* Y = side ? Yr : Yl;
    for (int nt = 0; nt < NT; nt++){
      h8 bfrag[KC];
#pragma unroll
      for (int c = 0; c < KC; c++)
        bfrag[c] = *reinterpret_cast<const h8*>(Wp + (size_t)((nt * KC + c) * 64 + lane) * 8);
      v4f acc0 = {0.f, 0.f, 0.f, 0.f}, acc1 = {0.f, 0.f, 0.f, 0.f};
#pragma unroll
      for (int c = 0; c < KC; c++){
        acc0 = __builtin_amdgcn_mfma_f32_16x16x32_f16(afrag[0][c], bfrag[c], acc0, 0, 0, 0);
        acc1 = __builtin_amdgcn_mfma_f32_16x16x32_f16(afrag[1][c], bfrag[c], acc1, 0, 0, 0);
      }
      int col = nt * 16 + (lane & 15);
      if (col < DO){
        float bv = bias[col];
        int rbase = row0 + mrow + ((lane >> 4) << 2);
#pragma unroll
        for (int r = 0; r < 4; r++){
          int row = rbase + r;
          if (row < NN) Yl[0] = Yl[0], Y[(size_t)row * DO + col] = (_Float16)(acc0[r] + bv);
          int row1 = rbase + 16 + r;
          if (row1 < NN) Y[(size_t)row1 * DO + col] = (_Float16)(acc1[r] + bv);
        }
      }
    }
  }
}

// ---------------- Fused GATv2 aggregate (packed fp16 MLP, fp32 softmax/acc) ---
__device__ __forceinline__ float edge_logit(h8 x, h8 xrv, h8 attv){
  h8 t = x + xrv;
  h8 l = __builtin_elementwise_max(t, t * (_Float16)SLOPE);
  const h2* lp = (const h2*)&l;
  const h2* ap = (const h2*)&attv;
  h2 d = lp[0] * ap[0];
  d += lp[1] * ap[1];
  d += lp[2] * ap[2];
  d += lp[3] * ap[3];
  return (float)d[0] + (float)d[1];
}

template<int LPG>
__device__ __forceinline__ float gsum(float v){
#pragma unroll
  for (int off = 1; off < LPG; off <<= 1) v += __shfl_xor(v, off, 64);
  return v;
}
template<int LPG>
__device__ __forceinline__ void gsum2(float& a, float& b){
#pragma unroll
  for (int off = 1; off < LPG; off <<= 1){
    a += __shfl_xor(a, off, 64);
    b += __shfl_xor(b, off, 64);
  }
}
template<int LPG>
__device__ __forceinline__ float gmax(float v){
#pragma unroll
  for (int off = 1; off < LPG; off <<= 1) v = fmaxf(v, __shfl_xor(v, off, 64));
  return v;
}

template<int DO, int LPG, int ACT, typename OT>
__global__ __launch_bounds__(256) void gat_agg(
    const _Float16* __restrict__ xl, const _Float16* __restrict__ xr,
    const int* __restrict__ csr_src, const int* __restrict__ row_ptr,
    const float* __restrict__ att, const float* __restrict__ bias,
    OT* __restrict__ out)
{
  constexpr int G = 64 / LPG;
  int wid = (blockIdx.x * 256 + threadIdx.x) >> 6;   // node
  int lane = threadIdx.x & 63;
  if (wid >= NN) return;
  int g = lane / LPG;
  int p = lane % LPG;
  int cbase = p * 8;
  bool ok = (LPG * 8 <= DO) ? true : (cbase < DO);

  h8 attv = hzero(), xrv = hzero();
  if (ok){
#pragma unroll
    for (int j = 0; j < 8; j++) attv[j] = (_Float16)att[cbase + j];
    xrv = *reinterpret_cast<const h8*>(xr + wid * DO + cbase);
  }

  float denA = 0.f, denB = 0.f;
  float accA[8], accB[8];
#pragma unroll
  for (int j = 0; j < 8; j++){ accA[j] = 0.f; accB[j] = 0.f; }

  // self loop (group 0 only)
  if (g == 0){
    h8 xlv = ok ? *reinterpret_cast<const h8*>(xl + wid * DO + cbase) : hzero();
    float s = gsum<LPG>(edge_logit(xlv, xrv, attv));
    float w = __expf(s);
    denA = w;
    f8 xf = __builtin_convertvector(xlv, f8);
#pragma unroll
    for (int j = 0; j < 8; j++) accA[j] = w * xf[j];
  }

  int e0 = row_ptr[wid], e1 = row_ptr[wid + 1];
  int e = e0 + g;
  while (e + G < e1){
    int sA = csr_src[e];
    int sB = csr_src[e + G];
    h8 xA = ok ? *reinterpret_cast<const h8*>(xl + sA * DO + cbase) : hzero();
    h8 xB = ok ? *reinterpret_cast<const h8*>(xl + sB * DO + cbase) : hzero();
    float pA = edge_logit(xA, xrv, attv);
    float pB = edge_logit(xB, xrv, attv);
    gsum2<LPG>(pA, pB);
    float wA = __expf(pA), wB = __expf(pB);
    denA += wA; denB += wB;
    f8 fA = __builtin_convertvector(xA, f8);
    f8 fB = __builtin_convertvector(xB, f8);
#pragma unroll
    for (int j = 0; j < 8; j++){
      accA[j] = fmaf(wA, fA[j], accA[j]);
      accB[j] = fmaf(wB, fB[j], accB[j]);
    }
    e += 2 * G;
  }
  if (e < e1){
    int sA = csr_src[e];
    h8 xA = ok ? *reinterpret_cast<const h8*>(xl + sA * DO + cbase) : hzero();
    float pA = gsum<LPG>(edge_logit(xA, xrv, attv));
    float w = __expf(pA);
    denA += w;
    f8 fA = __builtin_convertvector(xA, f8);
#pragma unroll
    for (int j = 0; j < 8; j++) accA[j] = fmaf(w, fA[j], accA[j]);
  }

  float den = denA + denB;
  float acc[8];
#pragma unroll
  for (int j = 0; j < 8; j++) acc[j] = accA[j] + accB[j];

#pragma unroll
  for (int off = LPG; off <= 32; off <<= 1){
    den += __shfl_xor(den, off, 64);
#pragma unroll
    for (int j = 0; j < 8; j++) acc[j] += __shfl_xor(acc[j], off, 64);
  }

  float inv = 1.0f / den;
  if (ACT == 0){
    if (g == 0 && ok){
      f8 vv;
#pragma unroll
      for (int j = 0; j < 8; j++) vv[j] = fmaxf(fmaf(acc[j], inv, bias[cbase + j]), 0.f);
      h8 o = __builtin_convertvector(vv, h8);
      *reinterpret_cast<h8*>((_Float16*)out + wid * DO + cbase) = o;
    }
  } else {
    float v[8]; float lmax = NEGX;
#pragma unroll
    for (int j = 0; j < 8; j++){
      v[j] = ok ? fmaf(acc[j], inv, bias[cbase + j]) : NEGX;
      lmax = fmaxf(lmax, v[j]);
    }
    lmax = gmax<LPG>(lmax);
    float lsum = 0.f;
#pragma unroll
    for (int j = 0; j < 8; j++) lsum += __expf(v[j] - lmax);
    lsum = gsum<LPG>(lsum);
    if (g == 0 && ok){
      float lg = lmax + __logf(lsum);
      float* op = (float*)out + wid * DO + cbase;
      float4 o0, o1;
      o0.x = v[0] - lg; o0.y = v[1] - lg; o0.z = v[2] - lg; o0.w = v[3] - lg;
      o1.x = v[4] - lg; o1.y = v[5] - lg; o1.z = v[6] - lg; o1.w = v[7] - lg;
      *reinterpret_cast<float4*>(op) = o0;
      *reinterpret_cast<float4*>(op + 4) = o1;
    }
  }
}

extern "C" void kernel_launch(void* const* d_in, const int* in_sizes, int n_in,
                              void* d_out, int out_size, void* d_ws, size_t ws_size,
                              hipStream_t stream) {
  const float* x   = (const float*)d_in[0];
  const int*   ei  = (const int*)d_in[1];
  const float* W1l = (const float*)d_in[2];  const float* W1r = (const float*)d_in[3];
  const float* b1l = (const float*)d_in[4];  const float* b1r = (const float*)d_in[5];
  const float* a1  = (const float*)d_in[6];  const float* c1  = (const float*)d_in[7];
  const float* W2l = (const float*)d_in[8];  const float* W2r = (const float*)d_in[9];
  const float* b2l = (const float*)d_in[10]; const float* b2r = (const float*)d_in[11];
  const float* a2  = (const float*)d_in[12]; const float* c2  = (const float*)d_in[13];
  const float* W3l = (const float*)d_in[14]; const float* W3r = (const float*)d_in[15];
  const float* b3l = (const float*)d_in[16]; const float* b3r = (const float*)d_in[17];
  const float* a3  = (const float*)d_in[18]; const float* c3  = (const float*)d_in[19];
  float* outp = (float*)d_out;

  // workspace layout (16B-aligned segments)
  _Float16* xl = (_Float16*)d_ws;         // 6,400,000 halves
  _Float16* xr = xl + 6400000;
  _Float16* h1 = xr + 6400000;
  _Float16* h2 = h1 + 6400000;            // 3,200,000 halves
  _Float16* wp1l = h2 + 3200000;          // packed weights (fp16), 16B-aligned
  _Float16* wp1r = wp1l + 32768;
  _Float16* wp2l = wp1r + 32768;
  _Float16* wp2r = wp2l + 8192;
  _Float16* wp3l = wp2r + 8192;
  _Float16* wp3r = wp3l + 3072;
  unsigned* pk   = (unsigned*)(wp3r + 3072);   // 800000
  int* csr_src   = (int*)(pk + NE);            // 800000
  int* row_ptr   = csr_src + NE;               // 50001
  int* gbp       = row_ptr + 50001;            // 65536 partial hist
  int* base      = gbp + 65536;                // 257
  int* bcur      = base + 257;                 // 256

  const int GB = (NN + 63) / 64;         // 782 gemm blocks
  const int AB = (NN * 64 + 255) / 256;  // 12500 agg blocks
  const int SB = (NE + CH - 1) / CH;     // 98 scatter blocks

  // pack weights + partial edge histogram (one launch)
  k_pack_hist<<<300, 256, 0, stream>>>(W1l, W1r, W2l, W2r, W3l, W3r,
                                       wp1l, wp1r, wp2l, wp2r, wp3l, wp3r,
                                       ei, gbp);
  k_scan<<<1, 256, 0, stream>>>(gbp, base, bcur, row_ptr);
  k_bscatter<<<SB, 256, 0, stream>>>(ei, bcur, pk);
  k_bcsr<<<196, 256, 0, stream>>>(pk, base, row_ptr, csr_src);

  // layer 1: 256 -> 128, relu
  gemm_mfma<float,256,128><<<GB, 128, 0, stream>>>(x, wp1l, b1l, wp1r, b1r, xl, xr);
  gat_agg<128,16,0,_Float16><<<AB, 256, 0, stream>>>(xl, xr, csr_src, row_ptr, a1, c1, h1);

  // layer 2: 128 -> 64, relu
  gemm_mfma<_Float16,128,64><<<GB, 128, 0, stream>>>(h1, wp2l, b2l, wp2r, b2r, xl, xr);
  gat_agg<64,8,0,_Float16><<<AB, 256, 0, stream>>>(xl, xr, csr_src, row_ptr, a2, c2, h2);

  // layer 3: 64 -> 40, bias + log_softmax fused
  gemm_mfma<_Float16,64,40><<<GB, 128, 0, stream>>>(h2, wp3l, b3l, wp3r, b3r, xl, xr);
  gat_agg<40,8,1,float><<<AB, 256, 0, stream>>>(xl, xr, csr_src, row_ptr, a3, c3, outp);
}

// Round 7
// 308.359 us; speedup vs baseline: 2.3368x; 1.1286x over previous
//
#include <hip/hip_runtime.h>
#include <math.h>

#define NN 50000
#define NE 800000
#define SLOPE 0.2f
#define NEGX (-1e30f)
#define CH 8192

typedef _Float16 h8 __attribute__((ext_vector_type(8)));
typedef _Float16 h4 __attribute__((ext_vector_type(4)));
typedef _Float16 h2 __attribute__((ext_vector_type(2)));
typedef float f8 __attribute__((ext_vector_type(8)));
typedef float v4f __attribute__((ext_vector_type(4)));

__device__ __forceinline__ h8 hzero(){ h8 z = {0,0,0,0,0,0,0,0}; return z; }

// ---------------- fused weight pack (fp16 fragment order) + edge histogram ----
__device__ __forceinline__ void pack_one(const float* __restrict__ W,
                                         _Float16* __restrict__ Wp,
                                         int DO, int K, int NT, int t){
  int KC = K >> 5;
  if (t >= NT * KC * 64) return;
  int lane = t & 63;
  int rest = t >> 6;
  int c  = rest % KC;
  int nt = rest / KC;
  int col = nt * 16 + (lane & 15);
  int k0  = c * 32 + ((lane >> 4) << 3);
  _Float16 o[8];
#pragma unroll
  for (int j = 0; j < 8; j++){
    float v = (col < DO) ? W[(k0 + j) * DO + col] : 0.f;
    o[j] = (_Float16)v;
  }
  *(ulonglong2*)(Wp + (size_t)t * 8) = *(ulonglong2*)o;
}

__global__ __launch_bounds__(256) void k_pack_hist(
    const float* W1l, const float* W1r, const float* W2l,
    const float* W2r, const float* W3l, const float* W3r,
    _Float16* p1l, _Float16* p1r, _Float16* p2l,
    _Float16* p2r, _Float16* p3l, _Float16* p3r,
    const int* __restrict__ ei, int* __restrict__ gbp){
  __shared__ int h[256];
  int b = blockIdx.x, t = threadIdx.x;
  if (b < 44){
    if      (b < 16) pack_one(W1l, p1l, 128, 256, 8, (b     ) * 256 + t);
    else if (b < 32) pack_one(W1r, p1r, 128, 256, 8, (b - 16) * 256 + t);
    else if (b < 36) pack_one(W2l, p2l,  64, 128, 4, (b - 32) * 256 + t);
    else if (b < 40) pack_one(W2r, p2r,  64, 128, 4, (b - 36) * 256 + t);
    else if (b < 42) pack_one(W3l, p3l,  40,  64, 3, (b - 40) * 256 + t);
    else             pack_one(W3r, p3r,  40,  64, 3, (b - 42) * 256 + t);
  } else {
    int hb = b - 44;                 // 0..63, each owns 12500 edges
    h[t] = 0;
    __syncthreads();
    int e0 = hb * 12500;
    for (int i = t; i < 12500; i += 256)
      atomicAdd(&h[ei[NE + e0 + i] >> 8], 1);
    __syncthreads();
    gbp[hb * 256 + t] = h[t];        // non-atomic partials
  }
}

__global__ __launch_bounds__(256) void k_scan(const int* __restrict__ gbp,
                                              int* __restrict__ base,
                                              int* __restrict__ bcur,
                                              int* __restrict__ row_ptr){
  __shared__ int s[256];
  int t = threadIdx.x;
  int v = 0;
#pragma unroll 8
  for (int i = 0; i < 64; i++) v += gbp[i * 256 + t];
  s[t] = v; __syncthreads();
  for (int off = 1; off < 256; off <<= 1){
    int a = (t >= off) ? s[t - off] : 0;
    __syncthreads(); s[t] += a; __syncthreads();
  }
  int ex = s[t] - v;
  base[t] = ex;
  bcur[t] = ex;
  if (t == 255){ base[256] = s[255]; row_ptr[NN] = s[255]; }
}

// pack: src (16b) | dstLow (8b) << 16 | bucket (8b) << 24
__global__ __launch_bounds__(256) void k_bscatter(const int* __restrict__ ei,
                                                  int* __restrict__ bcur,
                                                  unsigned* __restrict__ pk_out){
  __shared__ unsigned pk[CH];
  __shared__ int h[256];
  int t = threadIdx.x;
  int e0 = blockIdx.x * CH;
  h[t] = 0;
  __syncthreads();
  int n = NE - e0; if (n > CH) n = CH;
  for (int i = t; i < n; i += 256){
    int e = e0 + i;
    int s = ei[e], d = ei[NE + e];
    pk[i] = (unsigned)s | ((unsigned)(d & 255) << 16) | ((unsigned)(d >> 8) << 24);
    atomicAdd(&h[d >> 8], 1);
  }
  __syncthreads();
  int c = h[t];
  if (c) h[t] = atomicAdd(&bcur[t], c);
  __syncthreads();
  for (int i = t; i < n; i += 256){
    unsigned u = pk[i];
    int pos = atomicAdd(&h[u >> 24], 1);
    pk_out[pos] = u;
  }
}

__global__ __launch_bounds__(256) void k_bcsr(const unsigned* __restrict__ pk,
                                              const int* __restrict__ base,
                                              int* __restrict__ row_ptr,
                                              int* __restrict__ csr_src){
  __shared__ int h[256], s[256];
  int t = threadIdx.x;
  int b = blockIdx.x;
  int lo = base[b], hi = base[b + 1];
  h[t] = 0;
  __syncthreads();
  for (int i = lo + t; i < hi; i += 256)
    atomicAdd(&h[(pk[i] >> 16) & 255], 1);
  __syncthreads();
  int v = h[t];
  s[t] = v; __syncthreads();
  for (int off = 1; off < 256; off <<= 1){
    int a = (t >= off) ? s[t - off] : 0;
    __syncthreads(); s[t] += a; __syncthreads();
  }
  int ex = lo + s[t] - v;
  int node = b * 256 + t;
  if (node < NN) row_ptr[node] = ex;
  h[t] = ex;
  __syncthreads();
  for (int i = lo + t; i < hi; i += 256){
    unsigned u = pk[i];
    int pos = atomicAdd(&h[(u >> 16) & 255], 1);
    csr_src[pos] = (int)(u & 0xFFFFu);
  }
}

// ---------------- MFMA dual GEMM (f16): Yl = f16(X@Wl+bl), Yr = f16(X@Wr+br) ---
template<typename TI, int K, int DO>
__global__ __launch_bounds__(128) void gemm_mfma(
    const TI* __restrict__ X,
    const _Float16* __restrict__ Wpl, const float* __restrict__ bl,
    const _Float16* __restrict__ Wpr, const float* __restrict__ br,
    _Float16* __restrict__ Yl, _Float16* __restrict__ Yr)
{
  constexpr int KC = K / 32;
  constexpr int NT = (DO + 15) / 16;
  constexpr int LK = K + 8;
  __shared__ _Float16 As[64 * LK];

  int tid = threadIdx.x;
  int wave = tid >> 6, lane = tid & 63;
  int row0 = blockIdx.x * 64;

  if constexpr (sizeof(TI) == 4){
    constexpr int T4 = 64 * K / 4;
    for (int i = tid; i < T4; i += 128){
      int r  = i / (K / 4);
      int c4 = i % (K / 4);
      float4 v = make_float4(0.f, 0.f, 0.f, 0.f);
      if (row0 + r < NN) v = reinterpret_cast<const float4*>(X + (size_t)(row0 + r) * K)[c4];
      h4 o; o[0]=(_Float16)v.x; o[1]=(_Float16)v.y; o[2]=(_Float16)v.z; o[3]=(_Float16)v.w;
      *reinterpret_cast<h4*>(&As[r * LK + c4 * 4]) = o;
    }
  } else {
    constexpr int T8 = 64 * K / 8;
    for (int i = tid; i < T8; i += 128){
      int r  = i / (K / 8);
      int c8 = i % (K / 8);
      uint4 v = make_uint4(0u, 0u, 0u, 0u);
      if (row0 + r < NN)
        v = reinterpret_cast<const uint4*>(X + (size_t)(row0 + r) * K)[c8];
      *reinterpret_cast<uint4*>(&As[r * LK + c8 * 8]) = v;
    }
  }
  __syncthreads();

  int mrow = wave * 32;
  int arow = lane & 15;
  int aoff = (lane >> 4) << 3;
  h8 afrag[2][KC];
#pragma unroll
  for (int m = 0; m < 2; m++)
#pragma unroll
    for (int c = 0; c < KC; c++)
      afrag[m][c] = *reinterpret_cast<const h8*>(&As[(mrow + m * 16 + arow) * LK + c * 32 + aoff]);

#pragma unroll
  for (int side = 0; side < 2; side++){
    const _Float16* Wp = side ? Wpr : Wpl;
    const float* bias = side ? br : bl;
    _Float16* Y = side ? Yr : Yl;
    for (int nt = 0; nt < NT; nt++){
      h8 bfrag[KC];
#pragma unroll
      for (int c = 0; c < KC; c++)
        bfrag[c] = *reinterpret_cast<const h8*>(Wp + (size_t)((nt * KC + c) * 64 + lane) * 8);
      v4f acc0 = {0.f, 0.f, 0.f, 0.f}, acc1 = {0.f, 0.f, 0.f, 0.f};
#pragma unroll
      for (int c = 0; c < KC; c++){
        acc0 = __builtin_amdgcn_mfma_f32_16x16x32_f16(afrag[0][c], bfrag[c], acc0, 0, 0, 0);
        acc1 = __builtin_amdgcn_mfma_f32_16x16x32_f16(afrag[1][c], bfrag[c], acc1, 0, 0, 0);
      }
      int col = nt * 16 + (lane & 15);
      if (col < DO){
        float bv = bias[col];
        int rbase = row0 + mrow + ((lane >> 4) << 2);
#pragma unroll
        for (int r = 0; r < 4; r++){
          int row = rbase + r;
          if (row < NN) Y[(size_t)row * DO + col] = (_Float16)(acc0[r] + bv);
          int row1 = rbase + 16 + r;
          if (row1 < NN) Y[(size_t)row1 * DO + col] = (_Float16)(acc1[r] + bv);
        }
      }
    }
  }
}

// ---------------- Fused GATv2 aggregate: one GROUP per node ----------------
// Wave = G groups of LPG lanes; group g owns node wv*G+g. Group-uniform logits
// make den group-uniform (no cross-group merge at all). 2 unrolled states for
// memory parallelism. No max-subtract (Glorot logits are O(±8); exp safe).
__device__ __forceinline__ float edge_logit(h8 x, h8 xrv, h8 attv){
  h8 t = x + xrv;
  h8 l = __builtin_elementwise_max(t, t * (_Float16)SLOPE);
  const h2* lp = (const h2*)&l;
  const h2* ap = (const h2*)&attv;
  h2 d = lp[0] * ap[0];
  d += lp[1] * ap[1];
  d += lp[2] * ap[2];
  d += lp[3] * ap[3];
  return (float)d[0] + (float)d[1];
}

template<int LPG>
__device__ __forceinline__ float gsum(float v){
#pragma unroll
  for (int off = 1; off < LPG; off <<= 1) v += __shfl_xor(v, off, 64);
  return v;
}
template<int LPG>
__device__ __forceinline__ void gsum2(float& a, float& b){
#pragma unroll
  for (int off = 1; off < LPG; off <<= 1){
    a += __shfl_xor(a, off, 64);
    b += __shfl_xor(b, off, 64);
  }
}
template<int LPG>
__device__ __forceinline__ float gmax(float v){
#pragma unroll
  for (int off = 1; off < LPG; off <<= 1) v = fmaxf(v, __shfl_xor(v, off, 64));
  return v;
}

template<int DO, int LPG, int ACT, typename OT>
__global__ __launch_bounds__(256) void gat_agg(
    const _Float16* __restrict__ xl, const _Float16* __restrict__ xr,
    const int* __restrict__ csr_src, const int* __restrict__ row_ptr,
    const float* __restrict__ att, const float* __restrict__ bias,
    OT* __restrict__ out)
{
  constexpr int G = 64 / LPG;
  int lane = threadIdx.x & 63;
  int wv = (blockIdx.x * 256 + threadIdx.x) >> 6;
  int g = lane / LPG;
  int p = lane % LPG;
  int node = wv * G + g;
  if (node >= NN) return;
  int cbase = p * 8;
  bool ok = (LPG * 8 <= DO) ? true : (cbase < DO);

  h8 attv = hzero(), xrv = hzero(), xlv = hzero();
  if (ok){
    float4 a0 = *reinterpret_cast<const float4*>(att + cbase);
    float4 a1 = *reinterpret_cast<const float4*>(att + cbase + 4);
    attv[0]=(_Float16)a0.x; attv[1]=(_Float16)a0.y; attv[2]=(_Float16)a0.z; attv[3]=(_Float16)a0.w;
    attv[4]=(_Float16)a1.x; attv[5]=(_Float16)a1.y; attv[6]=(_Float16)a1.z; attv[7]=(_Float16)a1.w;
    xrv = *reinterpret_cast<const h8*>(xr + node * DO + cbase);
    xlv = *reinterpret_cast<const h8*>(xl + node * DO + cbase);
  }

  // self loop (every group, its own node)
  float s = gsum<LPG>(edge_logit(xlv, xrv, attv));
  float wS = __expf(s);
  float denA = wS, denB = 0.f;
  float accA[8], accB[8];
  {
    f8 xf = __builtin_convertvector(xlv, f8);
#pragma unroll
    for (int j = 0; j < 8; j++){ accA[j] = wS * xf[j]; accB[j] = 0.f; }
  }

  int e0 = row_ptr[node], e1 = row_ptr[node + 1];
  int e = e0;
  for (; e + 1 < e1; e += 2){
    int sA = csr_src[e], sB = csr_src[e + 1];
    h8 xA = ok ? *reinterpret_cast<const h8*>(xl + sA * DO + cbase) : hzero();
    h8 xB = ok ? *reinterpret_cast<const h8*>(xl + sB * DO + cbase) : hzero();
    float pA = edge_logit(xA, xrv, attv);
    float pB = edge_logit(xB, xrv, attv);
    gsum2<LPG>(pA, pB);
    float wA = __expf(pA), wB = __expf(pB);
    denA += wA; denB += wB;
    f8 fA = __builtin_convertvector(xA, f8);
    f8 fB = __builtin_convertvector(xB, f8);
#pragma unroll
    for (int j = 0; j < 8; j++){
      accA[j] = fmaf(wA, fA[j], accA[j]);
      accB[j] = fmaf(wB, fB[j], accB[j]);
    }
  }
  if (e < e1){
    int sA = csr_src[e];
    h8 xA = ok ? *reinterpret_cast<const h8*>(xl + sA * DO + cbase) : hzero();
    float pA = gsum<LPG>(edge_logit(xA, xrv, attv));
    float w = __expf(pA);
    denA += w;
    f8 fA = __builtin_convertvector(xA, f8);
#pragma unroll
    for (int j = 0; j < 8; j++) accA[j] = fmaf(w, fA[j], accA[j]);
  }

  float inv = 1.0f / (denA + denB);
  if (ACT == 0){
    if (ok){
      f8 vv;
#pragma unroll
      for (int j = 0; j < 4; j++){
        float bj;
        bj = bias[cbase + j];     vv[j]   = fmaxf(fmaf(accA[j] + accB[j], inv, bj), 0.f);
        bj = bias[cbase + 4 + j]; vv[4+j] = fmaxf(fmaf(accA[4+j] + accB[4+j], inv, bj), 0.f);
      }
      h8 o = __builtin_convertvector(vv, h8);
      *reinterpret_cast<h8*>((_Float16*)out + node * DO + cbase) = o;
    }
  } else {
    // DO=40: fused bias + log_softmax over the group
    float v[8]; float lmax = NEGX;
#pragma unroll
    for (int j = 0; j < 8; j++){
      v[j] = ok ? fmaf(accA[j] + accB[j], inv, bias[cbase + j]) : NEGX;
      lmax = fmaxf(lmax, v[j]);
    }
    lmax = gmax<LPG>(lmax);
    float lsum = 0.f;
#pragma unroll
    for (int j = 0; j < 8; j++) lsum += __expf(v[j] - lmax);   // idle lanes: exp(NEGX)=0
    lsum = gsum<LPG>(lsum);
    if (ok){
      float lg = lmax + __logf(lsum);
      float* op = (float*)out + node * DO + cbase;
      float4 o0, o1;
      o0.x = v[0] - lg; o0.y = v[1] - lg; o0.z = v[2] - lg; o0.w = v[3] - lg;
      o1.x = v[4] - lg; o1.y = v[5] - lg; o1.z = v[6] - lg; o1.w = v[7] - lg;
      *reinterpret_cast<float4*>(op) = o0;
      *reinterpret_cast<float4*>(op + 4) = o1;
    }
  }
}

extern "C" void kernel_launch(void* const* d_in, const int* in_sizes, int n_in,
                              void* d_out, int out_size, void* d_ws, size_t ws_size,
                              hipStream_t stream) {
  const float* x   = (const float*)d_in[0];
  const int*   ei  = (const int*)d_in[1];
  const float* W1l = (const float*)d_in[2];  const float* W1r = (const float*)d_in[3];
  const float* b1l = (const float*)d_in[4];  const float* b1r = (const float*)d_in[5];
  const float* a1  = (const float*)d_in[6];  const float* c1  = (const float*)d_in[7];
  const float* W2l = (const float*)d_in[8];  const float* W2r = (const float*)d_in[9];
  const float* b2l = (const float*)d_in[10]; const float* b2r = (const float*)d_in[11];
  const float* a2  = (const float*)d_in[12]; const float* c2  = (const float*)d_in[13];
  const float* W3l = (const float*)d_in[14]; const float* W3r = (const float*)d_in[15];
  const float* b3l = (const float*)d_in[16]; const float* b3r = (const float*)d_in[17];
  const float* a3  = (const float*)d_in[18]; const float* c3  = (const float*)d_in[19];
  float* outp = (float*)d_out;

  // workspace layout (16B-aligned segments)
  _Float16* xl = (_Float16*)d_ws;         // 6,400,000 halves
  _Float16* xr = xl + 6400000;
  _Float16* h1 = xr + 6400000;
  _Float16* h2 = h1 + 6400000;            // 3,200,000 halves
  _Float16* wp1l = h2 + 3200000;          // packed weights (fp16)
  _Float16* wp1r = wp1l + 32768;
  _Float16* wp2l = wp1r + 32768;
  _Float16* wp2r = wp2l + 8192;
  _Float16* wp3l = wp2r + 8192;
  _Float16* wp3r = wp3l + 3072;
  unsigned* pk   = (unsigned*)(wp3r + 3072);   // 800000
  int* csr_src   = (int*)(pk + NE);            // 800000
  int* row_ptr   = csr_src + NE;               // 50001
  int* gbp       = row_ptr + 50001;            // 64*256 partial hist
  int* base      = gbp + 16384;                // 257
  int* bcur      = base + 257;                 // 256

  const int GB = (NN + 63) / 64;         // 782 gemm blocks
  const int SB = (NE + CH - 1) / CH;     // 98 scatter blocks
  const int AB1 = (NN + 15) / 16;        // agg layer1: 16 nodes/block
  const int AB2 = (NN + 31) / 32;        // agg layers2/3: 32 nodes/block

  // pack weights + partial edge histogram (one launch)
  k_pack_hist<<<108, 256, 0, stream>>>(W1l, W1r, W2l, W2r, W3l, W3r,
                                       wp1l, wp1r, wp2l, wp2r, wp3l, wp3r,
                                       ei, gbp);
  k_scan<<<1, 256, 0, stream>>>(gbp, base, bcur, row_ptr);
  k_bscatter<<<SB, 256, 0, stream>>>(ei, bcur, pk);
  k_bcsr<<<196, 256, 0, stream>>>(pk, base, row_ptr, csr_src);

  // layer 1: 256 -> 128, relu
  gemm_mfma<float,256,128><<<GB, 128, 0, stream>>>(x, wp1l, b1l, wp1r, b1r, xl, xr);
  gat_agg<128,16,0,_Float16><<<AB1, 256, 0, stream>>>(xl, xr, csr_src, row_ptr, a1, c1, h1);

  // layer 2: 128 -> 64, relu
  gemm_mfma<_Float16,128,64><<<GB, 128, 0, stream>>>(h1, wp2l, b2l, wp2r, b2r, xl, xr);
  gat_agg<64,8,0,_Float16><<<AB2, 256, 0, stream>>>(xl, xr, csr_src, row_ptr, a2, c2, h2);

  // layer 3: 64 -> 40, bias + log_softmax fused
  gemm_mfma<_Float16,64,40><<<GB, 128, 0, stream>>>(h2, wp3l, b3l, wp3r, b3r, xl, xr);
  gat_agg<40,8,1,float><<<AB2, 256, 0, stream>>>(xl, xr, csr_src, row_ptr, a3, c3, outp);
}

// Round 8
// 296.664 us; speedup vs baseline: 2.4289x; 1.0394x over previous
//
#include <hip/hip_runtime.h>
#include <math.h>

#define NN 50000
#define NE 800000
#define SLOPE 0.2f
#define NEGX (-1e30f)
#define CH 8192

typedef _Float16 h8 __attribute__((ext_vector_type(8)));
typedef _Float16 h4 __attribute__((ext_vector_type(4)));
typedef _Float16 h2 __attribute__((ext_vector_type(2)));
typedef float f8 __attribute__((ext_vector_type(8)));
typedef float v4f __attribute__((ext_vector_type(4)));

__device__ __forceinline__ h8 hzero(){ h8 z = {0,0,0,0,0,0,0,0}; return z; }

// ---------------- fused weight pack (fp16 fragment order) + edge histogram ----
__device__ __forceinline__ void pack_one(const float* __restrict__ W,
                                         _Float16* __restrict__ Wp,
                                         int DO, int K, int NT, int t){
  int KC = K >> 5;
  if (t >= NT * KC * 64) return;
  int lane = t & 63;
  int rest = t >> 6;
  int c  = rest % KC;
  int nt = rest / KC;
  int col = nt * 16 + (lane & 15);
  int k0  = c * 32 + ((lane >> 4) << 3);
  _Float16 o[8];
#pragma unroll
  for (int j = 0; j < 8; j++){
    float v = (col < DO) ? W[(k0 + j) * DO + col] : 0.f;
    o[j] = (_Float16)v;
  }
  *(ulonglong2*)(Wp + (size_t)t * 8) = *(ulonglong2*)o;
}

__global__ __launch_bounds__(256) void k_pack_hist(
    const float* W1l, const float* W1r, const float* W2l,
    const float* W2r, const float* W3l, const float* W3r,
    _Float16* p1l, _Float16* p1r, _Float16* p2l,
    _Float16* p2r, _Float16* p3l, _Float16* p3r,
    const int* __restrict__ ei, int* __restrict__ gbp){
  __shared__ int h[256];
  int b = blockIdx.x, t = threadIdx.x;
  if (b < 44){
    if      (b < 16) pack_one(W1l, p1l, 128, 256, 8, (b     ) * 256 + t);
    else if (b < 32) pack_one(W1r, p1r, 128, 256, 8, (b - 16) * 256 + t);
    else if (b < 36) pack_one(W2l, p2l,  64, 128, 4, (b - 32) * 256 + t);
    else if (b < 40) pack_one(W2r, p2r,  64, 128, 4, (b - 36) * 256 + t);
    else if (b < 42) pack_one(W3l, p3l,  40,  64, 3, (b - 40) * 256 + t);
    else             pack_one(W3r, p3r,  40,  64, 3, (b - 42) * 256 + t);
  } else {
    int hb = b - 44;                 // 0..63, each owns 12500 edges
    h[t] = 0;
    __syncthreads();
    int e0 = hb * 12500;
    for (int i = t; i < 12500; i += 256)
      atomicAdd(&h[ei[NE + e0 + i] >> 8], 1);
    __syncthreads();
    gbp[hb * 256 + t] = h[t];        // non-atomic partials
  }
}

__global__ __launch_bounds__(256) void k_scan(const int* __restrict__ gbp,
                                              int* __restrict__ base,
                                              int* __restrict__ bcur,
                                              int* __restrict__ row_ptr){
  __shared__ int s[256];
  int t = threadIdx.x;
  int v = 0;
#pragma unroll 8
  for (int i = 0; i < 64; i++) v += gbp[i * 256 + t];
  s[t] = v; __syncthreads();
  for (int off = 1; off < 256; off <<= 1){
    int a = (t >= off) ? s[t - off] : 0;
    __syncthreads(); s[t] += a; __syncthreads();
  }
  int ex = s[t] - v;
  base[t] = ex;
  bcur[t] = ex;
  if (t == 255){ base[256] = s[255]; row_ptr[NN] = s[255]; }
}

// pack: src (16b) | dstLow (8b) << 16 | bucket (8b) << 24
__global__ __launch_bounds__(256) void k_bscatter(const int* __restrict__ ei,
                                                  int* __restrict__ bcur,
                                                  unsigned* __restrict__ pk_out){
  __shared__ unsigned pk[CH];
  __shared__ int h[256];
  int t = threadIdx.x;
  int e0 = blockIdx.x * CH;
  h[t] = 0;
  __syncthreads();
  int n = NE - e0; if (n > CH) n = CH;
  for (int i = t; i < n; i += 256){
    int e = e0 + i;
    int s = ei[e], d = ei[NE + e];
    pk[i] = (unsigned)s | ((unsigned)(d & 255) << 16) | ((unsigned)(d >> 8) << 24);
    atomicAdd(&h[d >> 8], 1);
  }
  __syncthreads();
  int c = h[t];
  if (c) h[t] = atomicAdd(&bcur[t], c);
  __syncthreads();
  for (int i = t; i < n; i += 256){
    unsigned u = pk[i];
    int pos = atomicAdd(&h[u >> 24], 1);
    pk_out[pos] = u;
  }
}

__global__ __launch_bounds__(256) void k_bcsr(const unsigned* __restrict__ pk,
                                              const int* __restrict__ base,
                                              int* __restrict__ row_ptr,
                                              int* __restrict__ csr_src){
  __shared__ int h[256], s[256];
  int t = threadIdx.x;
  int b = blockIdx.x;
  int lo = base[b], hi = base[b + 1];
  h[t] = 0;
  __syncthreads();
  for (int i = lo + t; i < hi; i += 256)
    atomicAdd(&h[(pk[i] >> 16) & 255], 1);
  __syncthreads();
  int v = h[t];
  s[t] = v; __syncthreads();
  for (int off = 1; off < 256; off <<= 1){
    int a = (t >= off) ? s[t - off] : 0;
    __syncthreads(); s[t] += a; __syncthreads();
  }
  int ex = lo + s[t] - v;
  int node = b * 256 + t;
  if (node < NN) row_ptr[node] = ex;
  h[t] = ex;
  __syncthreads();
  for (int i = lo + t; i < hi; i += 256){
    unsigned u = pk[i];
    int pos = atomicAdd(&h[(u >> 16) & 255], 1);
    csr_src[pos] = (int)(u & 0xFFFFu);
  }
}

// ---------------- Direct-load MFMA dual GEMM (no LDS, no barrier) -------------
// One 16-row m-tile per wave. A-fragments loaded straight from row-major X:
// lane reads rows (lane&15), k = (lane>>4)*8 + j — the 4 lane-groups cover
// k offsets +0/+8/+16/+24 of the same 16 rows => full-line coalescing, each
// line touched once. B streamed from packed (fragment-order) W in L2.
template<typename TI, int K, int DO>
__global__ __launch_bounds__(256, 4) void gemm_direct(
    const TI* __restrict__ X,
    const _Float16* __restrict__ Wpl, const float* __restrict__ bl,
    const _Float16* __restrict__ Wpr, const float* __restrict__ br,
    _Float16* __restrict__ Yl, _Float16* __restrict__ Yr)
{
  constexpr int KC = K / 32;
  constexpr int NT = (DO + 15) / 16;
  int lane = threadIdx.x & 63;
  int wv   = threadIdx.x >> 6;
  int row0 = (blockIdx.x * 4 + wv) * 16;   // m-tile base
  int arow = lane & 15;
  int koff = lane >> 4;
  int lrow = row0 + arow;
  int crow = (lrow < NN) ? lrow : 0;       // clamp loads; stores masked

  h8 afrag[KC];
  if constexpr (sizeof(TI) == 4){
    const float* Xr = (const float*)X + (size_t)crow * K + koff * 8;
#pragma unroll
    for (int c = 0; c < KC; c++){
      float4 v0 = *reinterpret_cast<const float4*>(Xr + c * 32);
      float4 v1 = *reinterpret_cast<const float4*>(Xr + c * 32 + 4);
      h8 a;
      a[0]=(_Float16)v0.x; a[1]=(_Float16)v0.y; a[2]=(_Float16)v0.z; a[3]=(_Float16)v0.w;
      a[4]=(_Float16)v1.x; a[5]=(_Float16)v1.y; a[6]=(_Float16)v1.z; a[7]=(_Float16)v1.w;
      afrag[c] = a;
    }
  } else {
    const _Float16* Xr = (const _Float16*)X + (size_t)crow * K + koff * 8;
#pragma unroll
    for (int c = 0; c < KC; c++)
      afrag[c] = *reinterpret_cast<const h8*>(Xr + c * 32);
  }

#pragma unroll
  for (int side = 0; side < 2; side++){
    const _Float16* Wp = side ? Wpr : Wpl;
    const float* bias = side ? br : bl;
    _Float16* Y = side ? Yr : Yl;
#pragma unroll
    for (int nt = 0; nt < NT; nt++){
      v4f acc = {0.f, 0.f, 0.f, 0.f};
#pragma unroll
      for (int c = 0; c < KC; c++){
        h8 b = *reinterpret_cast<const h8*>(Wp + (size_t)((nt * KC + c) * 64 + lane) * 8);
        acc = __builtin_amdgcn_mfma_f32_16x16x32_f16(afrag[c], b, acc, 0, 0, 0);
      }
      int col = nt * 16 + arow;            // C/D: col = lane&15
      if (col < DO){
        float bv = bias[col];
        int rbase = row0 + koff * 4;       // C/D: row = (lane>>4)*4 + reg
#pragma unroll
        for (int r = 0; r < 4; r++){
          int orow = rbase + r;
          if (orow < NN) Y[(size_t)orow * DO + col] = (_Float16)(acc[r] + bv);
        }
      }
    }
  }
}

// ---------------- Fused GATv2 aggregate: one GROUP per node ----------------
__device__ __forceinline__ float edge_logit(h8 x, h8 xrv, h8 attv){
  h8 t = x + xrv;
  h8 l = __builtin_elementwise_max(t, t * (_Float16)SLOPE);
  const h2* lp = (const h2*)&l;
  const h2* ap = (const h2*)&attv;
  h2 d = lp[0] * ap[0];
  d += lp[1] * ap[1];
  d += lp[2] * ap[2];
  d += lp[3] * ap[3];
  return (float)d[0] + (float)d[1];
}

template<int LPG>
__device__ __forceinline__ float gsum(float v){
#pragma unroll
  for (int off = 1; off < LPG; off <<= 1) v += __shfl_xor(v, off, 64);
  return v;
}
template<int LPG>
__device__ __forceinline__ void gsum2(float& a, float& b){
#pragma unroll
  for (int off = 1; off < LPG; off <<= 1){
    a += __shfl_xor(a, off, 64);
    b += __shfl_xor(b, off, 64);
  }
}
template<int LPG>
__device__ __forceinline__ float gmax(float v){
#pragma unroll
  for (int off = 1; off < LPG; off <<= 1) v = fmaxf(v, __shfl_xor(v, off, 64));
  return v;
}

template<int DO, int LPG, int ACT, typename OT>
__global__ __launch_bounds__(256) void gat_agg(
    const _Float16* __restrict__ xl, const _Float16* __restrict__ xr,
    const int* __restrict__ csr_src, const int* __restrict__ row_ptr,
    const float* __restrict__ att, const float* __restrict__ bias,
    OT* __restrict__ out)
{
  constexpr int G = 64 / LPG;
  int lane = threadIdx.x & 63;
  int wv = (blockIdx.x * 256 + threadIdx.x) >> 6;
  int g = lane / LPG;
  int p = lane % LPG;
  int node = wv * G + g;
  if (node >= NN) return;
  int cbase = p * 8;
  bool ok = (LPG * 8 <= DO) ? true : (cbase < DO);

  h8 attv = hzero(), xrv = hzero(), xlv = hzero();
  if (ok){
    float4 a0 = *reinterpret_cast<const float4*>(att + cbase);
    float4 a1 = *reinterpret_cast<const float4*>(att + cbase + 4);
    attv[0]=(_Float16)a0.x; attv[1]=(_Float16)a0.y; attv[2]=(_Float16)a0.z; attv[3]=(_Float16)a0.w;
    attv[4]=(_Float16)a1.x; attv[5]=(_Float16)a1.y; attv[6]=(_Float16)a1.z; attv[7]=(_Float16)a1.w;
    xrv = *reinterpret_cast<const h8*>(xr + node * DO + cbase);
    xlv = *reinterpret_cast<const h8*>(xl + node * DO + cbase);
  }

  // self loop (every group, its own node)
  float s = gsum<LPG>(edge_logit(xlv, xrv, attv));
  float wS = __expf(s);
  float denA = wS, denB = 0.f;
  float accA[8], accB[8];
  {
    f8 xf = __builtin_convertvector(xlv, f8);
#pragma unroll
    for (int j = 0; j < 8; j++){ accA[j] = wS * xf[j]; accB[j] = 0.f; }
  }

  int e0 = row_ptr[node], e1 = row_ptr[node + 1];
  int e = e0;
  for (; e + 1 < e1; e += 2){
    int sA = csr_src[e], sB = csr_src[e + 1];
    h8 xA = ok ? *reinterpret_cast<const h8*>(xl + sA * DO + cbase) : hzero();
    h8 xB = ok ? *reinterpret_cast<const h8*>(xl + sB * DO + cbase) : hzero();
    float pA = edge_logit(xA, xrv, attv);
    float pB = edge_logit(xB, xrv, attv);
    gsum2<LPG>(pA, pB);
    float wA = __expf(pA), wB = __expf(pB);
    denA += wA; denB += wB;
    f8 fA = __builtin_convertvector(xA, f8);
    f8 fB = __builtin_convertvector(xB, f8);
#pragma unroll
    for (int j = 0; j < 8; j++){
      accA[j] = fmaf(wA, fA[j], accA[j]);
      accB[j] = fmaf(wB, fB[j], accB[j]);
    }
  }
  if (e < e1){
    int sA = csr_src[e];
    h8 xA = ok ? *reinterpret_cast<const h8*>(xl + sA * DO + cbase) : hzero();
    float pA = gsum<LPG>(edge_logit(xA, xrv, attv));
    float w = __expf(pA);
    denA += w;
    f8 fA = __builtin_convertvector(xA, f8);
#pragma unroll
    for (int j = 0; j < 8; j++) accA[j] = fmaf(w, fA[j], accA[j]);
  }

  float inv = 1.0f / (denA + denB);
  if (ACT == 0){
    if (ok){
      f8 vv;
#pragma unroll
      for (int j = 0; j < 4; j++){
        float bj;
        bj = bias[cbase + j];     vv[j]   = fmaxf(fmaf(accA[j] + accB[j], inv, bj), 0.f);
        bj = bias[cbase + 4 + j]; vv[4+j] = fmaxf(fmaf(accA[4+j] + accB[4+j], inv, bj), 0.f);
      }
      h8 o = __builtin_convertvector(vv, h8);
      *reinterpret_cast<h8*>((_Float16*)out + node * DO + cbase) = o;
    }
  } else {
    // DO=40: fused bias + log_softmax over the group
    float v[8]; float lmax = NEGX;
#pragma unroll
    for (int j = 0; j < 8; j++){
      v[j] = ok ? fmaf(accA[j] + accB[j], inv, bias[cbase + j]) : NEGX;
      lmax = fmaxf(lmax, v[j]);
    }
    lmax = gmax<LPG>(lmax);
    float lsum = 0.f;
#pragma unroll
    for (int j = 0; j < 8; j++) lsum += __expf(v[j] - lmax);   // idle lanes: exp(NEGX)=0
    lsum = gsum<LPG>(lsum);
    if (ok){
      float lg = lmax + __logf(lsum);
      float* op = (float*)out + node * DO + cbase;
      float4 o0, o1;
      o0.x = v[0] - lg; o0.y = v[1] - lg; o0.z = v[2] - lg; o0.w = v[3] - lg;
      o1.x = v[4] - lg; o1.y = v[5] - lg; o1.z = v[6] - lg; o1.w = v[7] - lg;
      *reinterpret_cast<float4*>(op) = o0;
      *reinterpret_cast<float4*>(op + 4) = o1;
    }
  }
}

extern "C" void kernel_launch(void* const* d_in, const int* in_sizes, int n_in,
                              void* d_out, int out_size, void* d_ws, size_t ws_size,
                              hipStream_t stream) {
  const float* x   = (const float*)d_in[0];
  const int*   ei  = (const int*)d_in[1];
  const float* W1l = (const float*)d_in[2];  const float* W1r = (const float*)d_in[3];
  const float* b1l = (const float*)d_in[4];  const float* b1r = (const float*)d_in[5];
  const float* a1  = (const float*)d_in[6];  const float* c1  = (const float*)d_in[7];
  const float* W2l = (const float*)d_in[8];  const float* W2r = (const float*)d_in[9];
  const float* b2l = (const float*)d_in[10]; const float* b2r = (const float*)d_in[11];
  const float* a2  = (const float*)d_in[12]; const float* c2  = (const float*)d_in[13];
  const float* W3l = (const float*)d_in[14]; const float* W3r = (const float*)d_in[15];
  const float* b3l = (const float*)d_in[16]; const float* b3r = (const float*)d_in[17];
  const float* a3  = (const float*)d_in[18]; const float* c3  = (const float*)d_in[19];
  float* outp = (float*)d_out;

  // workspace layout (16B-aligned segments)
  _Float16* xl = (_Float16*)d_ws;         // 6,400,000 halves
  _Float16* xr = xl + 6400000;
  _Float16* h1 = xr + 6400000;
  _Float16* h2 = h1 + 6400000;            // 3,200,000 halves
  _Float16* wp1l = h2 + 3200000;          // packed weights (fp16)
  _Float16* wp1r = wp1l + 32768;
  _Float16* wp2l = wp1r + 32768;
  _Float16* wp2r = wp2l + 8192;
  _Float16* wp3l = wp2r + 8192;
  _Float16* wp3r = wp3l + 3072;
  unsigned* pk   = (unsigned*)(wp3r + 3072);   // 800000
  int* csr_src   = (int*)(pk + NE);            // 800000
  int* row_ptr   = csr_src + NE;               // 50001
  int* gbp       = row_ptr + 50001;            // 64*256 partial hist
  int* base      = gbp + 16384;                // 257
  int* bcur      = base + 257;                 // 256

  const int GB = (NN + 63) / 64;         // 782 gemm blocks (64 rows, 4 waves)
  const int SB = (NE + CH - 1) / CH;     // 98 scatter blocks
  const int AB1 = (NN + 15) / 16;        // agg layer1: 16 nodes/block
  const int AB2 = (NN + 31) / 32;        // agg layers2/3: 32 nodes/block

  // pack weights + partial edge histogram (one launch)
  k_pack_hist<<<108, 256, 0, stream>>>(W1l, W1r, W2l, W2r, W3l, W3r,
                                       wp1l, wp1r, wp2l, wp2r, wp3l, wp3r,
                                       ei, gbp);
  k_scan<<<1, 256, 0, stream>>>(gbp, base, bcur, row_ptr);
  k_bscatter<<<SB, 256, 0, stream>>>(ei, bcur, pk);
  k_bcsr<<<196, 256, 0, stream>>>(pk, base, row_ptr, csr_src);

  // layer 1: 256 -> 128, relu
  gemm_direct<float,256,128><<<GB, 256, 0, stream>>>(x, wp1l, b1l, wp1r, b1r, xl, xr);
  gat_agg<128,16,0,_Float16><<<AB1, 256, 0, stream>>>(xl, xr, csr_src, row_ptr, a1, c1, h1);

  // layer 2: 128 -> 64, relu
  gemm_direct<_Float16,128,64><<<GB, 256, 0, stream>>>(h1, wp2l, b2l, wp2r, b2r, xl, xr);
  gat_agg<64,8,0,_Float16><<<AB2, 256, 0, stream>>>(xl, xr, csr_src, row_ptr, a2, c2, h2);

  // layer 3: 64 -> 40, bias + log_softmax fused
  gemm_direct<_Float16,64,40><<<GB, 256, 0, stream>>>(h2, wp3l, b3l, wp3r, b3r, xl, xr);
  gat_agg<40,8,1,float><<<AB2, 256, 0, stream>>>(xl, xr, csr_src, row_ptr, a3, c3, outp);
}

// Round 9
// 286.919 us; speedup vs baseline: 2.5114x; 1.0340x over previous
//
#include <hip/hip_runtime.h>
#include <math.h>

#define NN 50000
#define NE 800000
#define SLOPE 0.2f
#define NEGX (-1e30f)
#define CH 8192

typedef _Float16 h8 __attribute__((ext_vector_type(8)));
typedef _Float16 h2 __attribute__((ext_vector_type(2)));
typedef float f8 __attribute__((ext_vector_type(8)));
typedef float v4f __attribute__((ext_vector_type(4)));

__device__ __forceinline__ h8 hzero(){ h8 z = {0,0,0,0,0,0,0,0}; return z; }

// ---------------- fused weight pack (fp16 fragment order) + edge histogram ----
__device__ __forceinline__ void pack_one(const float* __restrict__ W,
                                         _Float16* __restrict__ Wp,
                                         int DO, int K, int NT, int t){
  int KC = K >> 5;
  if (t >= NT * KC * 64) return;
  int lane = t & 63;
  int rest = t >> 6;
  int c  = rest % KC;
  int nt = rest / KC;
  int col = nt * 16 + (lane & 15);
  int k0  = c * 32 + ((lane >> 4) << 3);
  _Float16 o[8];
#pragma unroll
  for (int j = 0; j < 8; j++){
    float v = (col < DO) ? W[(k0 + j) * DO + col] : 0.f;
    o[j] = (_Float16)v;
  }
  *(ulonglong2*)(Wp + (size_t)t * 8) = *(ulonglong2*)o;
}

__global__ __launch_bounds__(256) void k_pack_hist(
    const float* W1l, const float* W1r, const float* W2l,
    const float* W2r, const float* W3l, const float* W3r,
    _Float16* p1l, _Float16* p1r, _Float16* p2l,
    _Float16* p2r, _Float16* p3l, _Float16* p3r,
    const int* __restrict__ ei, int* __restrict__ gbp){
  __shared__ int h[256];
  int b = blockIdx.x, t = threadIdx.x;
  if (b < 44){
    if      (b < 16) pack_one(W1l, p1l, 128, 256, 8, (b     ) * 256 + t);
    else if (b < 32) pack_one(W1r, p1r, 128, 256, 8, (b - 16) * 256 + t);
    else if (b < 36) pack_one(W2l, p2l,  64, 128, 4, (b - 32) * 256 + t);
    else if (b < 40) pack_one(W2r, p2r,  64, 128, 4, (b - 36) * 256 + t);
    else if (b < 42) pack_one(W3l, p3l,  40,  64, 3, (b - 40) * 256 + t);
    else             pack_one(W3r, p3r,  40,  64, 3, (b - 42) * 256 + t);
  } else {
    int hb = b - 44;                 // 0..63, each owns 12500 edges
    h[t] = 0;
    __syncthreads();
    int e0 = hb * 12500;
    for (int i = t; i < 12500; i += 256)
      atomicAdd(&h[ei[NE + e0 + i] >> 8], 1);
    __syncthreads();
    gbp[hb * 256 + t] = h[t];        // non-atomic partials
  }
}

__global__ __launch_bounds__(256) void k_scan(const int* __restrict__ gbp,
                                              int* __restrict__ base,
                                              int* __restrict__ bcur,
                                              int* __restrict__ row_ptr){
  __shared__ int s[256];
  int t = threadIdx.x;
  int v = 0;
#pragma unroll 8
  for (int i = 0; i < 64; i++) v += gbp[i * 256 + t];
  s[t] = v; __syncthreads();
  for (int off = 1; off < 256; off <<= 1){
    int a = (t >= off) ? s[t - off] : 0;
    __syncthreads(); s[t] += a; __syncthreads();
  }
  int ex = s[t] - v;
  base[t] = ex;
  bcur[t] = ex;
  if (t == 255){ base[256] = s[255]; row_ptr[NN] = s[255]; }
}

// pack: src (16b) | dstLow (8b) << 16 | bucket (8b) << 24
__global__ __launch_bounds__(256) void k_bscatter(const int* __restrict__ ei,
                                                  int* __restrict__ bcur,
                                                  unsigned* __restrict__ pk_out){
  __shared__ unsigned pk[CH];
  __shared__ int h[256];
  int t = threadIdx.x;
  int e0 = blockIdx.x * CH;
  h[t] = 0;
  __syncthreads();
  int n = NE - e0; if (n > CH) n = CH;
  for (int i = t; i < n; i += 256){
    int e = e0 + i;
    int s = ei[e], d = ei[NE + e];
    pk[i] = (unsigned)s | ((unsigned)(d & 255) << 16) | ((unsigned)(d >> 8) << 24);
    atomicAdd(&h[d >> 8], 1);
  }
  __syncthreads();
  int c = h[t];
  if (c) h[t] = atomicAdd(&bcur[t], c);
  __syncthreads();
  for (int i = t; i < n; i += 256){
    unsigned u = pk[i];
    int pos = atomicAdd(&h[u >> 24], 1);
    pk_out[pos] = u;
  }
}

__global__ __launch_bounds__(256) void k_bcsr(const unsigned* __restrict__ pk,
                                              const int* __restrict__ base,
                                              int* __restrict__ row_ptr,
                                              int* __restrict__ csr_src){
  __shared__ int h[256], s[256];
  int t = threadIdx.x;
  int b = blockIdx.x;
  int lo = base[b], hi = base[b + 1];
  h[t] = 0;
  __syncthreads();
  for (int i = lo + t; i < hi; i += 256)
    atomicAdd(&h[(pk[i] >> 16) & 255], 1);
  __syncthreads();
  int v = h[t];
  s[t] = v; __syncthreads();
  for (int off = 1; off < 256; off <<= 1){
    int a = (t >= off) ? s[t - off] : 0;
    __syncthreads(); s[t] += a; __syncthreads();
  }
  int ex = lo + s[t] - v;
  int node = b * 256 + t;
  if (node < NN) row_ptr[node] = ex;
  h[t] = ex;
  __syncthreads();
  for (int i = lo + t; i < hi; i += 256){
    unsigned u = pk[i];
    int pos = atomicAdd(&h[(u >> 16) & 255], 1);
    csr_src[pos] = (int)(u & 0xFFFFu);
  }
}

// ---------------- Direct-load MFMA dual GEMM (no LDS, no barrier) -------------
template<typename TI, int K, int DO>
__global__ __launch_bounds__(256, 4) void gemm_direct(
    const TI* __restrict__ X,
    const _Float16* __restrict__ Wpl, const float* __restrict__ bl,
    const _Float16* __restrict__ Wpr, const float* __restrict__ br,
    _Float16* __restrict__ Yl, _Float16* __restrict__ Yr)
{
  constexpr int KC = K / 32;
  constexpr int NT = (DO + 15) / 16;
  int lane = threadIdx.x & 63;
  int wv   = threadIdx.x >> 6;
  int row0 = (blockIdx.x * 4 + wv) * 16;   // m-tile base
  int arow = lane & 15;
  int koff = lane >> 4;
  int lrow = row0 + arow;
  int crow = (lrow < NN) ? lrow : 0;       // clamp loads; stores masked

  h8 afrag[KC];
  if constexpr (sizeof(TI) == 4){
    const float* Xr = (const float*)X + (size_t)crow * K + koff * 8;
#pragma unroll
    for (int c = 0; c < KC; c++){
      float4 v0 = *reinterpret_cast<const float4*>(Xr + c * 32);
      float4 v1 = *reinterpret_cast<const float4*>(Xr + c * 32 + 4);
      h8 a;
      a[0]=(_Float16)v0.x; a[1]=(_Float16)v0.y; a[2]=(_Float16)v0.z; a[3]=(_Float16)v0.w;
      a[4]=(_Float16)v1.x; a[5]=(_Float16)v1.y; a[6]=(_Float16)v1.z; a[7]=(_Float16)v1.w;
      afrag[c] = a;
    }
  } else {
    const _Float16* Xr = (const _Float16*)X + (size_t)crow * K + koff * 8;
#pragma unroll
    for (int c = 0; c < KC; c++)
      afrag[c] = *reinterpret_cast<const h8*>(Xr + c * 32);
  }

#pragma unroll
  for (int side = 0; side < 2; side++){
    const _Float16* Wp = side ? Wpr : Wpl;
    const float* bias = side ? br : bl;
    _Float16* Y = side ? Yr : Yl;
#pragma unroll
    for (int nt = 0; nt < NT; nt++){
      v4f acc = {0.f, 0.f, 0.f, 0.f};
#pragma unroll
      for (int c = 0; c < KC; c++){
        h8 b = *reinterpret_cast<const h8*>(Wp + (size_t)((nt * KC + c) * 64 + lane) * 8);
        acc = __builtin_amdgcn_mfma_f32_16x16x32_f16(afrag[c], b, acc, 0, 0, 0);
      }
      int col = nt * 16 + arow;            // C/D: col = lane&15
      if (col < DO){
        float bv = bias[col];
        int rbase = row0 + koff * 4;       // C/D: row = (lane>>4)*4 + reg
#pragma unroll
        for (int r = 0; r < 4; r++){
          int orow = rbase + r;
          if (orow < NN) Y[(size_t)orow * DO + col] = (_Float16)(acc[r] + bv);
        }
      }
    }
  }
}

// ---------------- agg helpers ----------------
__device__ __forceinline__ float edge_logit(h8 x, h8 xrv, h8 attv){
  h8 t = x + xrv;
  h8 l = __builtin_elementwise_max(t, t * (_Float16)SLOPE);
  const h2* lp = (const h2*)&l;
  const h2* ap = (const h2*)&attv;
  h2 d = lp[0] * ap[0];
  d += lp[1] * ap[1];
  d += lp[2] * ap[2];
  d += lp[3] * ap[3];
  return (float)d[0] + (float)d[1];
}

template<int LPG>
__device__ __forceinline__ float gsum(float v){
#pragma unroll
  for (int off = 1; off < LPG; off <<= 1) v += __shfl_xor(v, off, 64);
  return v;
}
template<int LPG>
__device__ __forceinline__ void gsum2(float& a, float& b){
#pragma unroll
  for (int off = 1; off < LPG; off <<= 1){
    a += __shfl_xor(a, off, 64);
    b += __shfl_xor(b, off, 64);
  }
}
template<int LPG>
__device__ __forceinline__ float gmax(float v){
#pragma unroll
  for (int off = 1; off < LPG; off <<= 1) v = fmaxf(v, __shfl_xor(v, off, 64));
  return v;
}

// ---------------- Fused agg(layer l) + gemm(layer l+1) ----------------
// Requires LPG*8 == DO (all lanes active). Block = 4 waves = NPB = 4*(64/LPG)
// nodes; agg writes h rows to LDS (+8-half pad); then waves compute the
// 16-row m-tile dual GEMM of the next layer straight from LDS.
template<int DO, int LPG, int DO2>
__global__ __launch_bounds__(256) void agg_gemm(
    const _Float16* __restrict__ xl, const _Float16* __restrict__ xr,
    const int* __restrict__ csr_src, const int* __restrict__ row_ptr,
    const float* __restrict__ att, const float* __restrict__ bias,
    const _Float16* __restrict__ Wpl2, const float* __restrict__ bl2,
    const _Float16* __restrict__ Wpr2, const float* __restrict__ br2,
    _Float16* __restrict__ Yl, _Float16* __restrict__ Yr)
{
  constexpr int G = 64 / LPG;
  constexpr int NPB = 4 * G;            // nodes per block
  constexpr int LK = DO + 8;            // padded LDS row stride (halves)
  constexpr int KC2 = DO / 32;
  constexpr int NT2 = (DO2 + 15) / 16;
  constexpr int MT = NPB / 16;          // m-tiles per block (1 or 2)
  __shared__ _Float16 hs[NPB * LK];

  int lane = threadIdx.x & 63;
  int wid  = threadIdx.x >> 6;
  int g = lane / LPG, p = lane % LPG;
  int nodeLocal = wid * G + g;
  int node = blockIdx.x * NPB + nodeLocal;
  int cbase = p * 8;
  bool nvalid = node < NN;
  int nodeC = nvalid ? node : 0;

  // ---- agg phase ----
  h8 attv, xrv, xlv;
  {
    float4 a0 = *reinterpret_cast<const float4*>(att + cbase);
    float4 a1 = *reinterpret_cast<const float4*>(att + cbase + 4);
    attv[0]=(_Float16)a0.x; attv[1]=(_Float16)a0.y; attv[2]=(_Float16)a0.z; attv[3]=(_Float16)a0.w;
    attv[4]=(_Float16)a1.x; attv[5]=(_Float16)a1.y; attv[6]=(_Float16)a1.z; attv[7]=(_Float16)a1.w;
    xrv = *reinterpret_cast<const h8*>(xr + nodeC * DO + cbase);
    xlv = *reinterpret_cast<const h8*>(xl + nodeC * DO + cbase);
  }
  float s = gsum<LPG>(edge_logit(xlv, xrv, attv));
  float wS = __expf(s);
  float denA = wS, denB = 0.f;
  float accA[8], accB[8];
  {
    f8 xf = __builtin_convertvector(xlv, f8);
#pragma unroll
    for (int j = 0; j < 8; j++){ accA[j] = wS * xf[j]; accB[j] = 0.f; }
  }

  int e0 = row_ptr[nodeC];
  int e1 = nvalid ? row_ptr[nodeC + 1] : e0;
  int e = e0;
  for (; e + 1 < e1; e += 2){
    int sA = csr_src[e], sB = csr_src[e + 1];
    h8 xA = *reinterpret_cast<const h8*>(xl + sA * DO + cbase);
    h8 xB = *reinterpret_cast<const h8*>(xl + sB * DO + cbase);
    float pA = edge_logit(xA, xrv, attv);
    float pB = edge_logit(xB, xrv, attv);
    gsum2<LPG>(pA, pB);
    float wA = __expf(pA), wB = __expf(pB);
    denA += wA; denB += wB;
    f8 fA = __builtin_convertvector(xA, f8);
    f8 fB = __builtin_convertvector(xB, f8);
#pragma unroll
    for (int j = 0; j < 8; j++){
      accA[j] = fmaf(wA, fA[j], accA[j]);
      accB[j] = fmaf(wB, fB[j], accB[j]);
    }
  }
  if (e < e1){
    int sA = csr_src[e];
    h8 xA = *reinterpret_cast<const h8*>(xl + sA * DO + cbase);
    float pA = gsum<LPG>(edge_logit(xA, xrv, attv));
    float w = __expf(pA);
    denA += w;
    f8 fA = __builtin_convertvector(xA, f8);
#pragma unroll
    for (int j = 0; j < 8; j++) accA[j] = fmaf(w, fA[j], accA[j]);
  }

  {
    float inv = 1.0f / (denA + denB);
    f8 vv;
#pragma unroll
    for (int j = 0; j < 8; j++)
      vv[j] = fmaxf(fmaf(accA[j] + accB[j], inv, bias[cbase + j]), 0.f);
    h8 ho = __builtin_convertvector(vv, h8);
    *reinterpret_cast<h8*>(&hs[nodeLocal * LK + cbase]) = ho;
  }
  __syncthreads();

  // ---- gemm phase: next layer, A from LDS, B from packed W (L2) ----
  int arow = lane & 15;
  int koff = lane >> 4;
  int mt = (MT == 1) ? 0 : (wid >> 1);
  h8 afrag[KC2];
#pragma unroll
  for (int c = 0; c < KC2; c++)
    afrag[c] = *reinterpret_cast<const h8*>(&hs[(mt * 16 + arow) * LK + koff * 8 + c * 32]);

  int row0 = blockIdx.x * NPB + mt * 16;
  int side = wid & 1;
  const _Float16* Wp = side ? Wpr2 : Wpl2;
  const float* bias2 = side ? br2 : bl2;
  _Float16* Y = side ? Yr : Yl;
  int nt_begin = (MT == 1) ? (wid >> 1) * (NT2 / 2) : 0;
  int nt_end   = (MT == 1) ? nt_begin + NT2 / 2 : NT2;
  for (int nt = nt_begin; nt < nt_end; nt++){
    v4f acc = {0.f, 0.f, 0.f, 0.f};
#pragma unroll
    for (int c = 0; c < KC2; c++){
      h8 b = *reinterpret_cast<const h8*>(Wp + (size_t)((nt * KC2 + c) * 64 + lane) * 8);
      acc = __builtin_amdgcn_mfma_f32_16x16x32_f16(afrag[c], b, acc, 0, 0, 0);
    }
    int col = nt * 16 + arow;
    if (col < DO2){
      float bv = bias2[col];
      int rbase = row0 + koff * 4;
#pragma unroll
      for (int r = 0; r < 4; r++){
        int orow = rbase + r;
        if (orow < NN) Y[(size_t)orow * DO2 + col] = (_Float16)(acc[r] + bv);
      }
    }
  }
}

// ---------------- Final GATv2 aggregate + bias + log_softmax ----------------
template<int DO, int LPG>
__global__ __launch_bounds__(256) void gat_agg_out(
    const _Float16* __restrict__ xl, const _Float16* __restrict__ xr,
    const int* __restrict__ csr_src, const int* __restrict__ row_ptr,
    const float* __restrict__ att, const float* __restrict__ bias,
    float* __restrict__ out)
{
  constexpr int G = 64 / LPG;
  int lane = threadIdx.x & 63;
  int wv = (blockIdx.x * 256 + threadIdx.x) >> 6;
  int g = lane / LPG;
  int p = lane % LPG;
  int node = wv * G + g;
  if (node >= NN) return;
  int cbase = p * 8;
  bool ok = (cbase < DO);

  h8 attv = hzero(), xrv = hzero(), xlv = hzero();
  if (ok){
    float4 a0 = *reinterpret_cast<const float4*>(att + cbase);
    float4 a1 = *reinterpret_cast<const float4*>(att + cbase + 4);
    attv[0]=(_Float16)a0.x; attv[1]=(_Float16)a0.y; attv[2]=(_Float16)a0.z; attv[3]=(_Float16)a0.w;
    attv[4]=(_Float16)a1.x; attv[5]=(_Float16)a1.y; attv[6]=(_Float16)a1.z; attv[7]=(_Float16)a1.w;
    xrv = *reinterpret_cast<const h8*>(xr + node * DO + cbase);
    xlv = *reinterpret_cast<const h8*>(xl + node * DO + cbase);
  }

  float s = gsum<LPG>(edge_logit(xlv, xrv, attv));
  float wS = __expf(s);
  float denA = wS, denB = 0.f;
  float accA[8], accB[8];
  {
    f8 xf = __builtin_convertvector(xlv, f8);
#pragma unroll
    for (int j = 0; j < 8; j++){ accA[j] = wS * xf[j]; accB[j] = 0.f; }
  }

  int e0 = row_ptr[node], e1 = row_ptr[node + 1];
  int e = e0;
  for (; e + 1 < e1; e += 2){
    int sA = csr_src[e], sB = csr_src[e + 1];
    h8 xA = ok ? *reinterpret_cast<const h8*>(xl + sA * DO + cbase) : hzero();
    h8 xB = ok ? *reinterpret_cast<const h8*>(xl + sB * DO + cbase) : hzero();
    float pA = edge_logit(xA, xrv, attv);
    float pB = edge_logit(xB, xrv, attv);
    gsum2<LPG>(pA, pB);
    float wA = __expf(pA), wB = __expf(pB);
    denA += wA; denB += wB;
    f8 fA = __builtin_convertvector(xA, f8);
    f8 fB = __builtin_convertvector(xB, f8);
#pragma unroll
    for (int j = 0; j < 8; j++){
      accA[j] = fmaf(wA, fA[j], accA[j]);
      accB[j] = fmaf(wB, fB[j], accB[j]);
    }
  }
  if (e < e1){
    int sA = csr_src[e];
    h8 xA = ok ? *reinterpret_cast<const h8*>(xl + sA * DO + cbase) : hzero();
    float pA = gsum<LPG>(edge_logit(xA, xrv, attv));
    float w = __expf(pA);
    denA += w;
    f8 fA = __builtin_convertvector(xA, f8);
#pragma unroll
    for (int j = 0; j < 8; j++) accA[j] = fmaf(w, fA[j], accA[j]);
  }

  float inv = 1.0f / (denA + denB);
  float v[8]; float lmax = NEGX;
#pragma unroll
  for (int j = 0; j < 8; j++){
    v[j] = ok ? fmaf(accA[j] + accB[j], inv, bias[cbase + j]) : NEGX;
    lmax = fmaxf(lmax, v[j]);
  }
  lmax = gmax<LPG>(lmax);
  float lsum = 0.f;
#pragma unroll
  for (int j = 0; j < 8; j++) lsum += __expf(v[j] - lmax);   // idle lanes: exp(NEGX)=0
  lsum = gsum<LPG>(lsum);
  if (ok){
    float lg = lmax + __logf(lsum);
    float* op = (float*)out + node * DO + cbase;
    float4 o0, o1;
    o0.x = v[0] - lg; o0.y = v[1] - lg; o0.z = v[2] - lg; o0.w = v[3] - lg;
    o1.x = v[4] - lg; o1.y = v[5] - lg; o1.z = v[6] - lg; o1.w = v[7] - lg;
    *reinterpret_cast<float4*>(op) = o0;
    *reinterpret_cast<float4*>(op + 4) = o1;
  }
}

extern "C" void kernel_launch(void* const* d_in, const int* in_sizes, int n_in,
                              void* d_out, int out_size, void* d_ws, size_t ws_size,
                              hipStream_t stream) {
  const float* x   = (const float*)d_in[0];
  const int*   ei  = (const int*)d_in[1];
  const float* W1l = (const float*)d_in[2];  const float* W1r = (const float*)d_in[3];
  const float* b1l = (const float*)d_in[4];  const float* b1r = (const float*)d_in[5];
  const float* a1  = (const float*)d_in[6];  const float* c1  = (const float*)d_in[7];
  const float* W2l = (const float*)d_in[8];  const float* W2r = (const float*)d_in[9];
  const float* b2l = (const float*)d_in[10]; const float* b2r = (const float*)d_in[11];
  const float* a2  = (const float*)d_in[12]; const float* c2  = (const float*)d_in[13];
  const float* W3l = (const float*)d_in[14]; const float* W3r = (const float*)d_in[15];
  const float* b3l = (const float*)d_in[16]; const float* b3r = (const float*)d_in[17];
  const float* a3  = (const float*)d_in[18]; const float* c3  = (const float*)d_in[19];
  float* outp = (float*)d_out;

  // workspace layout (16B-aligned segments)
  _Float16* xl1 = (_Float16*)d_ws;        // 50000*128
  _Float16* xr1 = xl1 + 6400000;
  _Float16* xl2 = xr1 + 6400000;          // 50000*64
  _Float16* xr2 = xl2 + 3200000;
  _Float16* xl3 = xr2 + 3200000;          // 50000*40
  _Float16* xr3 = xl3 + 2000000;
  _Float16* wp1l = xr3 + 2000000;         // packed weights (fp16)
  _Float16* wp1r = wp1l + 32768;
  _Float16* wp2l = wp1r + 32768;
  _Float16* wp2r = wp2l + 8192;
  _Float16* wp3l = wp2r + 8192;
  _Float16* wp3r = wp3l + 3072;
  unsigned* pk   = (unsigned*)(wp3r + 3072);   // 800000
  int* csr_src   = (int*)(pk + NE);            // 800000
  int* row_ptr   = csr_src + NE;               // 50001
  int* gbp       = row_ptr + 50001;            // 64*256 partial hist
  int* base      = gbp + 16384;                // 257
  int* bcur      = base + 257;                 // 256

  const int GB = (NN + 63) / 64;          // 782 gemm1 blocks (64 rows, 4 waves)
  const int SB = (NE + CH - 1) / CH;      // 98 scatter blocks
  const int FB1 = (NN + 15) / 16;         // fused agg1+gemm2: 16 nodes/block
  const int FB2 = (NN + 31) / 32;         // fused agg2+gemm3: 32 nodes/block
  const int AB3 = (NN + 31) / 32;         // agg3: 32 nodes/block (LPG=8)

  // pack weights + partial edge histogram (one launch)
  k_pack_hist<<<108, 256, 0, stream>>>(W1l, W1r, W2l, W2r, W3l, W3r,
                                       wp1l, wp1r, wp2l, wp2r, wp3l, wp3r,
                                       ei, gbp);
  k_scan<<<1, 256, 0, stream>>>(gbp, base, bcur, row_ptr);
  k_bscatter<<<SB, 256, 0, stream>>>(ei, bcur, pk);
  k_bcsr<<<196, 256, 0, stream>>>(pk, base, row_ptr, csr_src);

  // layer 1 GEMM: x (fp32) -> xl1, xr1
  gemm_direct<float,256,128><<<GB, 256, 0, stream>>>(x, wp1l, b1l, wp1r, b1r, xl1, xr1);

  // fused: agg layer1 (relu) + gemm layer2 -> xl2, xr2
  agg_gemm<128,16,64><<<FB1, 256, 0, stream>>>(xl1, xr1, csr_src, row_ptr,
                                               a1, c1, wp2l, b2l, wp2r, b2r, xl2, xr2);

  // fused: agg layer2 (relu) + gemm layer3 -> xl3, xr3
  agg_gemm<64,8,40><<<FB2, 256, 0, stream>>>(xl2, xr2, csr_src, row_ptr,
                                             a2, c2, wp3l, b3l, wp3r, b3r, xl3, xr3);

  // final: agg layer3 + bias + log_softmax -> out
  gat_agg_out<40,8><<<AB3, 256, 0, stream>>>(xl3, xr3, csr_src, row_ptr, a3, c3, outp);
}